// Round 5
// baseline (7997.495 us; speedup 1.0000x reference)
//
#include <hip/hip_runtime.h>
#include <hip/hip_bf16.h>

// Problem constants
#define NB 32
#define NT 1024
#define IH 180
#define IW 330
#define KSZ 37
#define HP (IH + KSZ)         // 217
#define WP (IW + KSZ)         // 367
#define H1 90
#define W1 165
#define H2 45
#define W2 82
#define PIX2 (H2*W2)          // 3690
#define CH1 32
#define CH2 64
#define CH3 128

// Per-batch f32 element counts (no overlays)
#define EL_PAD  (HP*WP)           // 79,639
#define EL_HEAT (IH*IW)           // 59,400
#define EL_OUT1 (CH1*H1*W1)       // 475,200
#define EL_OUT2 (CH2*PIX2)        // 236,160
#define EL_MAP3 (CH3*PIX2)        // 472,320
#define EL_PX   (CH3*CH3)         // 16,384
#define EL_PER_BATCH (EL_PAD + EL_HEAT + EL_OUT1 + EL_OUT2 + 4*EL_MAP3 + EL_PX) // 2,756,063

// ---------------------------------------------------------------------------
// K0: zero the padded heat buffer
// ---------------------------------------------------------------------------
__global__ __launch_bounds__(256) void zero_k(float* __restrict__ p, int n) {
    int i = blockIdx.x * 256 + threadIdx.x;
    if (i < n) p[i] = 0.0f;
}

// ---------------------------------------------------------------------------
// K1: literal scatter. One thread per (local batch, point). Global atomics
// into the padded (HP x WP) buffer, exactly mirroring the reference.
// ---------------------------------------------------------------------------
__global__ __launch_bounds__(256) void heat_scatter(const float* __restrict__ x_t,
                                                    float* __restrict__ heatpad,
                                                    int b0, int gb) {
    __shared__ float k1n[KSZ];
    const int tid = threadIdx.x;
    if (tid < KSZ) {
        float ax = (float)tid - 18.0f;
        k1n[tid] = expf(-ax * ax / 18.0f);   // 2*sigma^2 = 18
    }
    __syncthreads();
    if (tid == 0) {
        float s = 0.0f;
        for (int i = 0; i < KSZ; i++) s += k1n[i];
        float inv = 1.0f / s;                 // kern/(sum)^2 via per-axis /sum
        for (int i = 0; i < KSZ; i++) k1n[i] *= inv;
    }
    __syncthreads();

    int t = blockIdx.x * 256 + tid;
    if (t >= gb * NT) return;
    int lb = t / NT;
    int p  = t % NT;
    int b  = b0 + lb;

    float x = x_t[(size_t)(b * NT + p) * 2 + 0];
    float y = x_t[(size_t)(b * NT + p) * 2 + 1];
    if (isnan(x) || isnan(y)) return;
    int xp = IH - (int)((x - 30.0f) * 180.0f);
    int yp = (int)((y - 120.0f) * 165.0f);
    int xs = min(max(xp - 18, 0), IH - 36);
    int xe = min(max(xp + 18, 0), IH);
    int ys = min(max(yp - 18, 0), IW - 36);
    int ye = min(max(yp + 18, 0), IW);
    int nr = xe - xs, nc = ye - ys;

    float* hb = heatpad + (size_t)lb * EL_PAD;
    for (int r = 0; r < KSZ; r++) {
        if (r >= nr) break;
        float wr = k1n[r];
        float* rowp = hb + (size_t)(xs + r) * WP + ys;
        for (int c = 0; c < KSZ; c++) {
            if (c >= nc) break;
            atomicAdd(&rowp[c], wr * k1n[c]);
        }
    }
}

// ---------------------------------------------------------------------------
// K2: per-(local)batch max over the cropped region of the padded heat
// ---------------------------------------------------------------------------
__global__ __launch_bounds__(256) void heat_max(const float* __restrict__ heatpad,
                                                float* __restrict__ m) {
    const int lb = blockIdx.x;
    const float* hb = heatpad + (size_t)lb * EL_PAD;
    float mx = -INFINITY;
    for (int i = threadIdx.x; i < EL_HEAT; i += 256) {
        int y = i / IW, x = i % IW;
        mx = fmaxf(mx, hb[(size_t)y * WP + x]);
    }
    __shared__ float red[256];
    red[threadIdx.x] = mx;
    __syncthreads();
    for (int s = 128; s > 0; s >>= 1) {
        if (threadIdx.x < s) red[threadIdx.x] = fmaxf(red[threadIdx.x], red[threadIdx.x + s]);
        __syncthreads();
    }
    if (threadIdx.x == 0) m[lb] = red[0];
}

// ---------------------------------------------------------------------------
// K2b: fused = 0.7*(heat/(m+1e-10)) + 0.3*image   (literal)
// ---------------------------------------------------------------------------
__global__ __launch_bounds__(256) void fuse_k(const float* __restrict__ heatpad,
                                              const float* __restrict__ image,
                                              const float* __restrict__ m,
                                              float* __restrict__ fused,
                                              int b0, int gb) {
    int t = blockIdx.x * 256 + threadIdx.x;
    if (t >= gb * EL_HEAT) return;
    int lb = t / EL_HEAT;
    int r  = t % EL_HEAT;
    int y = r / IW, x = r % IW;
    float hv = heatpad[(size_t)lb * EL_PAD + (size_t)y * WP + x];
    float hn = hv / (m[lb] + 1e-10f);
    float iv = image[(size_t)(b0 + lb) * EL_HEAT + r];
    fused[(size_t)lb * EL_HEAT + r] = 0.7f * hn + 0.3f * iv;
}

// ---------------------------------------------------------------------------
// K3: conv1(1->32) + BN + relu + pool on fused
// ---------------------------------------------------------------------------
__global__ __launch_bounds__(256) void conv1_pool(const float* __restrict__ fused,
                                                  const float* __restrict__ w,
                                                  const float* __restrict__ cb,
                                                  const float* __restrict__ g,
                                                  const float* __restrict__ bb,
                                                  float* __restrict__ out1,
                                                  int gb) {
    __shared__ float ws_[CH1 * 9];
    __shared__ float bs_[CH1];
    const int tid = threadIdx.x;
    for (int i = tid; i < CH1 * 9; i += 256) {
        int oc = i / 9;
        ws_[i] = w[i] * g[oc];
    }
    if (tid < CH1) bs_[tid] = cb[tid] * g[tid] + bb[tid];
    __syncthreads();

    int t = blockIdx.x * 256 + tid;
    if (t >= gb * H1 * W1) return;
    int lb = t / (H1 * W1);
    int r = t % (H1 * W1);
    int py = r / W1, px = r % W1;
    const float* fb = fused + (size_t)lb * EL_HEAT;

    float v[4][4];
    int y0 = 2 * py - 1, x0 = 2 * px - 1;
#pragma unroll
    for (int i = 0; i < 4; i++) {
#pragma unroll
        for (int j = 0; j < 4; j++) {
            int y = y0 + i, x = x0 + j;
            v[i][j] = (y >= 0 && y < IH && x >= 0 && x < IW) ? fb[(size_t)y * IW + x] : 0.0f;
        }
    }
    for (int oc = 0; oc < CH1; oc++) {
        float a00 = 0, a01 = 0, a10 = 0, a11 = 0;
        const float* wp = &ws_[oc * 9];
#pragma unroll
        for (int ky = 0; ky < 3; ky++) {
#pragma unroll
            for (int kx = 0; kx < 3; kx++) {
                float wv = wp[ky * 3 + kx];
                a00 += wv * v[ky][kx];
                a01 += wv * v[ky][kx + 1];
                a10 += wv * v[ky + 1][kx];
                a11 += wv * v[ky + 1][kx + 1];
            }
        }
        float bias = bs_[oc];
        a00 = fmaxf(a00 + bias, 0.0f);
        a01 = fmaxf(a01 + bias, 0.0f);
        a10 = fmaxf(a10 + bias, 0.0f);
        a11 = fmaxf(a11 + bias, 0.0f);
        float mx = fmaxf(fmaxf(a00, a01), fmaxf(a10, a11));
        out1[(((size_t)lb * CH1 + oc) * H1 + py) * W1 + px] = mx;
    }
}

// ---------------------------------------------------------------------------
// K4: conv2(32->64) + BN + relu + pool
// ---------------------------------------------------------------------------
__global__ __launch_bounds__(256) void conv2_pool(const float* __restrict__ in,
                                                  const float* __restrict__ w,
                                                  const float* __restrict__ cb,
                                                  const float* __restrict__ g,
                                                  const float* __restrict__ bb,
                                                  float* __restrict__ out) {
    __shared__ float ws_[8 * CH1 * 9];
    __shared__ float bs_[8];
    const int tid = threadIdx.x;
    const int ocg = blockIdx.y;
    const int lb = blockIdx.z;
    for (int i = tid; i < 8 * CH1 * 9; i += 256) {
        int o = i / (CH1 * 9);
        int rest = i % (CH1 * 9);
        int oc = ocg * 8 + o;
        ws_[i] = w[(size_t)oc * CH1 * 9 + rest] * g[oc];
    }
    if (tid < 8) {
        int oc = ocg * 8 + tid;
        bs_[tid] = cb[oc] * g[oc] + bb[oc];
    }
    __syncthreads();

    int pid = blockIdx.x * 256 + tid;
    if (pid >= PIX2) return;
    int py = pid / W2, px = pid % W2;
    float acc[8][4];
#pragma unroll
    for (int o = 0; o < 8; o++)
#pragma unroll
        for (int q = 0; q < 4; q++) acc[o][q] = 0.0f;

    int y0 = 2 * py - 1, x0 = 2 * px - 1;
    for (int ic = 0; ic < CH1; ic++) {
        float v[4][4];
        const float* ip = in + ((size_t)lb * CH1 + ic) * H1 * W1;
#pragma unroll
        for (int i = 0; i < 4; i++) {
#pragma unroll
            for (int j = 0; j < 4; j++) {
                int y = y0 + i, x = x0 + j;
                v[i][j] = (y >= 0 && y < H1 && x >= 0 && x < W1) ? ip[(size_t)y * W1 + x] : 0.0f;
            }
        }
#pragma unroll
        for (int o = 0; o < 8; o++) {
            const float* wp = &ws_[(o * CH1 + ic) * 9];
#pragma unroll
            for (int ky = 0; ky < 3; ky++) {
#pragma unroll
                for (int kx = 0; kx < 3; kx++) {
                    float wv = wp[ky * 3 + kx];
                    acc[o][0] += wv * v[ky][kx];
                    acc[o][1] += wv * v[ky][kx + 1];
                    acc[o][2] += wv * v[ky + 1][kx];
                    acc[o][3] += wv * v[ky + 1][kx + 1];
                }
            }
        }
    }
#pragma unroll
    for (int o = 0; o < 8; o++) {
        float bias = bs_[o];
        float a0 = fmaxf(acc[o][0] + bias, 0.0f);
        float a1 = fmaxf(acc[o][1] + bias, 0.0f);
        float a2 = fmaxf(acc[o][2] + bias, 0.0f);
        float a3 = fmaxf(acc[o][3] + bias, 0.0f);
        float mx = fmaxf(fmaxf(a0, a1), fmaxf(a2, a3));
        out[(((size_t)lb * CH2 + ocg * 8 + o) * H2 + py) * W2 + px] = mx;
    }
}

// ---------------------------------------------------------------------------
// K5-K8: 3x3 'SAME' conv at 45x82, IC -> 128 out channels, relu or sigmoid
// ---------------------------------------------------------------------------
template <int IC, bool SIG>
__global__ __launch_bounds__(256) void conv3x3(const float* __restrict__ in,
                                               const float* __restrict__ w,
                                               const float* __restrict__ cb,
                                               const float* __restrict__ g,
                                               const float* __restrict__ bb,
                                               float* __restrict__ out) {
    __shared__ float ws_[8 * IC * 9];
    __shared__ float bs_[8];
    const int tid = threadIdx.x;
    const int ocg = blockIdx.y;
    const int lb = blockIdx.z;
    for (int i = tid; i < 8 * IC * 9; i += 256) {
        int o = i / (IC * 9);
        int rest = i % (IC * 9);
        int oc = ocg * 8 + o;
        ws_[i] = w[(size_t)oc * IC * 9 + rest] * g[oc];
    }
    if (tid < 8) {
        int oc = ocg * 8 + tid;
        bs_[tid] = cb[oc] * g[oc] + bb[oc];
    }
    __syncthreads();

    int pid = blockIdx.x * 256 + tid;
    if (pid >= PIX2) return;
    int py = pid / W2, px = pid % W2;
    float acc[8];
#pragma unroll
    for (int o = 0; o < 8; o++) acc[o] = 0.0f;

    for (int ic = 0; ic < IC; ic++) {
        float v[9];
        const float* ip = in + ((size_t)lb * IC + ic) * PIX2;
#pragma unroll
        for (int ky = 0; ky < 3; ky++) {
#pragma unroll
            for (int kx = 0; kx < 3; kx++) {
                int y = py + ky - 1, x = px + kx - 1;
                v[ky * 3 + kx] = (y >= 0 && y < H2 && x >= 0 && x < W2) ? ip[(size_t)y * W2 + x] : 0.0f;
            }
        }
#pragma unroll
        for (int o = 0; o < 8; o++) {
            const float* wp = &ws_[(o * IC + ic) * 9];
#pragma unroll
            for (int k = 0; k < 9; k++) acc[o] += wp[k] * v[k];
        }
    }
#pragma unroll
    for (int o = 0; o < 8; o++) {
        float z = acc[o] + bs_[o];
        if (SIG) z = 1.0f / (1.0f + expf(-z));
        else z = fmaxf(z, 0.0f);
        out[(((size_t)lb * CH3 + ocg * 8 + o) * H2 + py) * W2 + px] = z;
    }
}

// ---------------------------------------------------------------------------
// K9: per-(local)batch min/max of p2 output
// ---------------------------------------------------------------------------
__global__ __launch_bounds__(256) void pminmax(const float* __restrict__ p,
                                               float* __restrict__ mm) {
    const int lb = blockIdx.x;
    const float* pb = p + (size_t)lb * EL_MAP3;
    float mn = INFINITY, mx = -INFINITY;
    for (int i = threadIdx.x; i < EL_MAP3; i += 256) {
        float v = pb[i];
        mn = fminf(mn, v);
        mx = fmaxf(mx, v);
    }
    __shared__ float rmn[256], rmx[256];
    rmn[threadIdx.x] = mn; rmx[threadIdx.x] = mx;
    __syncthreads();
    for (int s = 128; s > 0; s >>= 1) {
        if (threadIdx.x < s) {
            rmn[threadIdx.x] = fminf(rmn[threadIdx.x], rmn[threadIdx.x + s]);
            rmx[threadIdx.x] = fmaxf(rmx[threadIdx.x], rmx[threadIdx.x + s]);
        }
        __syncthreads();
    }
    if (threadIdx.x == 0) { mm[lb * 2] = rmn[0]; mm[lb * 2 + 1] = rmx[0]; }
}

// ---------------------------------------------------------------------------
// K10: p_map = sigmoid(10*((p-min)/max(max-min,1e-4) - 0.5))  (in place)
// ---------------------------------------------------------------------------
__global__ __launch_bounds__(256) void pmap_k(float* __restrict__ p,
                                              const float* __restrict__ mm,
                                              int n) {
    int i = blockIdx.x * 256 + threadIdx.x;
    if (i >= n) return;
    int lb = i / EL_MAP3;
    float mn = mm[lb * 2], mx = mm[lb * 2 + 1];
    float denom = fmaxf(mx - mn, 1e-4f);
    float v = (p[i] - mn) / denom;
    p[i] = 1.0f / (1.0f + expf(-10.0f * (v - 0.5f)));
}

// ---------------------------------------------------------------------------
// K11: p_x[lb,p,c] = (1/3690) * sum_hw pmap[lb,p,hw]*fx[lb,c,hw]
// ---------------------------------------------------------------------------
__global__ __launch_bounds__(256) void einsum_k(const float* __restrict__ pm,
                                                const float* __restrict__ fx,
                                                float* __restrict__ px) {
    const int lb = blockIdx.z;
    const int pt = blockIdx.y;
    const int ct = blockIdx.x;
    __shared__ float As[32][65], Bs[32][65];
    const int tid = threadIdx.x;
    const int ty = tid / 16, tx = tid % 16;
    float acc00 = 0, acc01 = 0, acc10 = 0, acc11 = 0;
    const float* A = pm + ((size_t)lb * CH3 + pt * 32) * PIX2;
    const float* Bp = fx + ((size_t)lb * CH3 + ct * 32) * PIX2;
    for (int kk = 0; kk < PIX2; kk += 64) {
        for (int l = tid; l < 2048; l += 256) {
            int row = l >> 6, k = l & 63;
            int gk = kk + k;
            float av = 0, bv = 0;
            if (gk < PIX2) {
                av = A[(size_t)row * PIX2 + gk];
                bv = Bp[(size_t)row * PIX2 + gk];
            }
            As[row][k] = av;
            Bs[row][k] = bv;
        }
        __syncthreads();
#pragma unroll
        for (int k = 0; k < 64; k++) {
            float a0 = As[2 * ty][k], a1 = As[2 * ty + 1][k];
            float b0 = Bs[2 * tx][k], b1 = Bs[2 * tx + 1][k];
            acc00 += a0 * b0; acc01 += a0 * b1;
            acc10 += a1 * b0; acc11 += a1 * b1;
        }
        __syncthreads();
    }
    const float inv = 1.0f / (float)PIX2;
    int p0 = pt * 32 + 2 * ty, c0 = ct * 32 + 2 * tx;
    px[((size_t)lb * CH3 + p0) * CH3 + c0] = acc00 * inv;
    px[((size_t)lb * CH3 + p0) * CH3 + c0 + 1] = acc01 * inv;
    px[((size_t)lb * CH3 + p0 + 1) * CH3 + c0] = acc10 * inv;
    px[((size_t)lb * CH3 + p0 + 1) * CH3 + c0 + 1] = acc11 * inv;
}

// ---------------------------------------------------------------------------
// K12: out[b0+lb,o] = sum_k px[lb,k]*fc_w[o,k] + fc_b[o]  (FLOAT32 output —
// the reference returns f32; writing bf16 was the round-3/4 failure)
// ---------------------------------------------------------------------------
__global__ __launch_bounds__(256) void fc_k(const float* __restrict__ px,
                                            const float* __restrict__ w,
                                            const float* __restrict__ bias,
                                            float* __restrict__ out,
                                            int b0) {
    const int gw = blockIdx.x * 4 + (threadIdx.x >> 6);
    const int lane = threadIdx.x & 63;
    const int lb = gw >> 8;
    const int o = gw & 255;
    const float* xb = px + (size_t)lb * EL_PX;
    const float* wr = w + (size_t)o * EL_PX;
    float s = 0.0f;
    for (int k = lane; k < EL_PX; k += 64) s += xb[k] * wr[k];
#pragma unroll
    for (int off = 32; off > 0; off >>= 1) s += __shfl_down(s, off);
    if (lane == 0) out[(size_t)(b0 + lb) * 256 + o] = s + bias[o];
}

// ---------------------------------------------------------------------------
extern "C" void kernel_launch(void* const* d_in, const int* in_sizes, int n_in,
                              void* d_out, int out_size, void* d_ws, size_t ws_size,
                              hipStream_t stream) {
    const float* x_t   = (const float*)d_in[0];
    const float* image = (const float*)d_in[1];
    const float* c1_w  = (const float*)d_in[2];
    const float* c1_b  = (const float*)d_in[3];
    const float* bn1_g = (const float*)d_in[4];
    const float* bn1_b = (const float*)d_in[5];
    const float* c2_w  = (const float*)d_in[6];
    const float* c2_b  = (const float*)d_in[7];
    const float* bn2_g = (const float*)d_in[8];
    const float* bn2_b = (const float*)d_in[9];
    const float* a1_w  = (const float*)d_in[10];
    const float* a1_b  = (const float*)d_in[11];
    const float* abn1_g= (const float*)d_in[12];
    const float* abn1_b= (const float*)d_in[13];
    const float* a2_w  = (const float*)d_in[14];
    const float* a2_b  = (const float*)d_in[15];
    const float* abn2_g= (const float*)d_in[16];
    const float* abn2_b= (const float*)d_in[17];
    const float* p1_w  = (const float*)d_in[18];
    const float* p1_b  = (const float*)d_in[19];
    const float* pbn1_g= (const float*)d_in[20];
    const float* pbn1_b= (const float*)d_in[21];
    const float* p2_w  = (const float*)d_in[22];
    const float* p2_b  = (const float*)d_in[23];
    const float* pbn2_g= (const float*)d_in[24];
    const float* pbn2_b= (const float*)d_in[25];
    const float* fc_w  = (const float*)d_in[26];
    const float* fc_b  = (const float*)d_in[27];
    float* outp = (float*)d_out;

    // Largest batch-group whose (overlay-free) f32 footprint fits ws_size.
    int GB = 32;
    while (GB > 1) {
        size_t need = ((size_t)GB * EL_PER_BATCH + 128) * sizeof(float);
        if (need <= ws_size) break;
        GB >>= 1;
    }
    const int ngroups = NB / GB;

    float* ws = (float*)d_ws;
    float* heatpad = ws;                                    // GB*EL_PAD
    float* m       = heatpad + (size_t)GB * EL_PAD;         // 64
    float* fused   = m + 64;                                // GB*EL_HEAT
    float* out1    = fused + (size_t)GB * EL_HEAT;          // GB*EL_OUT1
    float* out2    = out1 + (size_t)GB * EL_OUT1;           // GB*EL_OUT2
    float* fbuf    = out2 + (size_t)GB * EL_OUT2;           // GB*EL_MAP3
    float* fx      = fbuf + (size_t)GB * EL_MAP3;           // GB*EL_MAP3
    float* pp1     = fx + (size_t)GB * EL_MAP3;             // GB*EL_MAP3
    float* pp2     = pp1 + (size_t)GB * EL_MAP3;            // GB*EL_MAP3
    float* pmm     = pp2 + (size_t)GB * EL_MAP3;            // 64
    float* px      = pmm + 64;                              // GB*EL_PX

    const int ptiles = (PIX2 + 255) / 256;   // 15

    for (int gidx = 0; gidx < ngroups; ++gidx) {
        const int b0 = gidx * GB;
        // K0: zero padded heat
        {
            int n = GB * EL_PAD;
            zero_k<<<(n + 255) / 256, 256, 0, stream>>>(heatpad, n);
        }
        // K1: literal scatter
        heat_scatter<<<(GB * NT + 255) / 256, 256, 0, stream>>>(x_t, heatpad, b0, GB);
        // K2: per-batch max over crop
        heat_max<<<GB, 256, 0, stream>>>(heatpad, m);
        // K2b: fused
        {
            int n = GB * EL_HEAT;
            fuse_k<<<(n + 255) / 256, 256, 0, stream>>>(heatpad, image, m, fused, b0, GB);
        }
        // K3: conv1+pool
        conv1_pool<<<(GB * H1 * W1 + 255) / 256, 256, 0, stream>>>(
            fused, c1_w, c1_b, bn1_g, bn1_b, out1, GB);
        // K4: conv2+pool
        conv2_pool<<<dim3(ptiles, CH2 / 8, GB), 256, 0, stream>>>(
            out1, c2_w, c2_b, bn2_g, bn2_b, out2);
        // K5: a1 (relu)
        conv3x3<CH2, false><<<dim3(ptiles, CH3 / 8, GB), 256, 0, stream>>>(
            out2, a1_w, a1_b, abn1_g, abn1_b, fbuf);
        // K6: a2 (sigmoid) -> fx
        conv3x3<CH3, true><<<dim3(ptiles, CH3 / 8, GB), 256, 0, stream>>>(
            fbuf, a2_w, a2_b, abn2_g, abn2_b, fx);
        // K7: p1 (relu) -> pp1
        conv3x3<CH2, false><<<dim3(ptiles, CH3 / 8, GB), 256, 0, stream>>>(
            out2, p1_w, p1_b, pbn1_g, pbn1_b, pp1);
        // K8: p2 (relu) -> pp2
        conv3x3<CH3, false><<<dim3(ptiles, CH3 / 8, GB), 256, 0, stream>>>(
            pp1, p2_w, p2_b, pbn2_g, pbn2_b, pp2);
        // K9: min/max
        pminmax<<<GB, 256, 0, stream>>>(pp2, pmm);
        // K10: sigmoid map (in place)
        {
            int n = GB * EL_MAP3;
            pmap_k<<<(n + 255) / 256, 256, 0, stream>>>(pp2, pmm, n);
        }
        // K11: einsum -> px
        einsum_k<<<dim3(4, 4, GB), 256, 0, stream>>>(pp2, fx, px);
        // K12: FC -> out (f32)
        fc_k<<<GB * 64, 256, 0, stream>>>(px, fc_w, fc_b, outp, b0);
    }
}

// Round 6
// 4352.009 us; speedup vs baseline: 1.8377x; 1.8377x over previous
//
#include <hip/hip_runtime.h>
#include <hip/hip_bf16.h>

// Problem constants
#define NB 32
#define NT 1024
#define IH 180
#define IW 330
#define KSZ 37
#define H1 90
#define W1 165
#define H2 45
#define W2 82
#define PIX2 (H2*W2)          // 3690
#define CH1 32
#define CH2 64
#define CH3 128

// Per-batch f32 element counts
#define EL_HEAT (IH*IW)           // 59,400
#define EL_OUT1 (CH1*H1*W1)       // 475,200
#define EL_OUT2 (CH2*PIX2)        // 236,160
#define EL_MAP3 (CH3*PIX2)        // 472,320
#define EL_PX   (CH3*CH3)         // 16,384
#define EL_PER_BATCH (2*EL_HEAT + EL_OUT1 + EL_OUT2 + 4*EL_MAP3 + EL_PX) // 2,735,824

// folded-weight sizes (bf16 shorts): wT[tap][oc=128][ic]
#define WSH_A1 (9*128*64)         // 73,728
#define WSH_A2 (9*128*128)        // 147,456
#define WSH_TOT (2*WSH_A1 + 2*WSH_A2)  // 442,368 shorts = 221,184 float slots

typedef __attribute__((ext_vector_type(8))) short short8;   // 8 bf16 = 4 VGPRs
typedef __attribute__((ext_vector_type(4))) float floatx4;

// ---------------------------------------------------------------------------
// K1: heatmap scatter via LDS strips. One block per (strip, local batch).
// Strip = 64 columns of the 180x330 crop; every element written -> no pre-zero.
// Index math identical to the (validated) literal version; all patches land
// inside the crop (xs<=144, ys<=294).
// ---------------------------------------------------------------------------
__global__ __launch_bounds__(256) void heat_scatter(const float* __restrict__ x_t,
                                                    float* __restrict__ heat,
                                                    int b0) {
    const int strip = blockIdx.x;          // 6 strips of 64 cols
    const int lb = blockIdx.y;
    const int b = b0 + lb;
    const int c0 = strip * 64;
    const int cw = min(64, IW - c0);
    __shared__ float lds[IH * 64];
    __shared__ float k1n[KSZ];
    const int tid = threadIdx.x;

    if (tid < KSZ) {
        float ax = (float)tid - 18.0f;
        k1n[tid] = expf(-ax * ax / 18.0f);   // 2*sigma^2 = 18
    }
    for (int i = tid; i < IH * 64; i += 256) lds[i] = 0.0f;
    __syncthreads();
    if (tid == 0) {
        float s = 0.0f;
        for (int i = 0; i < KSZ; i++) s += k1n[i];
        float inv = 1.0f / s;
        for (int i = 0; i < KSZ; i++) k1n[i] *= inv;
    }
    __syncthreads();

    for (int p = tid; p < NT; p += 256) {
        float x = x_t[(size_t)(b * NT + p) * 2 + 0];
        float y = x_t[(size_t)(b * NT + p) * 2 + 1];
        if (isnan(x) || isnan(y)) continue;
        int xp = IH - (int)((x - 30.0f) * 180.0f);
        int yp = (int)((y - 120.0f) * 165.0f);
        int xs = min(max(xp - 18, 0), IH - 36);
        int xe = min(max(xp + 18, 0), IH);
        int ys = min(max(yp - 18, 0), IW - 36);
        int ye = min(max(yp + 18, 0), IW);
        int nr = xe - xs, nc = ye - ys;
        if (nr <= 0 || nc <= 0) continue;
        int cbeg = max(ys, c0);
        int cend = min(ys + nc, c0 + cw);
        if (cbeg >= cend) continue;
        for (int r = 0; r < nr; r++) {
            float wr = k1n[r];
            float* row = &lds[(xs + r) * 64 - c0];
            for (int col = cbeg; col < cend; col++) {
                atomicAdd(&row[col], wr * k1n[col - ys]);
            }
        }
    }
    __syncthreads();
    for (int i = tid; i < IH * cw; i += 256) {
        int row = i / cw, col = i % cw;
        heat[((size_t)lb * IH + row) * IW + c0 + col] = lds[row * 64 + col];
    }
}

// ---------------------------------------------------------------------------
// K2: per-(local)batch max of heat (contiguous crop layout)
// ---------------------------------------------------------------------------
__global__ __launch_bounds__(256) void heat_max(const float* __restrict__ heat,
                                                float* __restrict__ m) {
    const int lb = blockIdx.x;
    const float* hb = heat + (size_t)lb * EL_HEAT;
    float mx = -INFINITY;
    for (int i = threadIdx.x; i < EL_HEAT; i += 256) mx = fmaxf(mx, hb[i]);
    __shared__ float red[256];
    red[threadIdx.x] = mx;
    __syncthreads();
    for (int s = 128; s > 0; s >>= 1) {
        if (threadIdx.x < s) red[threadIdx.x] = fmaxf(red[threadIdx.x], red[threadIdx.x + s]);
        __syncthreads();
    }
    if (threadIdx.x == 0) m[lb] = red[0];
}

// ---------------------------------------------------------------------------
// K2b: fused = 0.7*(heat/(m+1e-10)) + 0.3*image
// ---------------------------------------------------------------------------
__global__ __launch_bounds__(256) void fuse_k(const float* __restrict__ heat,
                                              const float* __restrict__ image,
                                              const float* __restrict__ m,
                                              float* __restrict__ fused,
                                              int b0, int gb) {
    int t = blockIdx.x * 256 + threadIdx.x;
    if (t >= gb * EL_HEAT) return;
    int lb = t / EL_HEAT;
    int r  = t % EL_HEAT;
    float hn = heat[(size_t)lb * EL_HEAT + r] / (m[lb] + 1e-10f);
    float iv = image[(size_t)(b0 + lb) * EL_HEAT + r];
    fused[(size_t)lb * EL_HEAT + r] = 0.7f * hn + 0.3f * iv;
}

// ---------------------------------------------------------------------------
// K3: conv1(1->32) + BN + relu + pool
// ---------------------------------------------------------------------------
__global__ __launch_bounds__(256) void conv1_pool(const float* __restrict__ fused,
                                                  const float* __restrict__ w,
                                                  const float* __restrict__ cb,
                                                  const float* __restrict__ g,
                                                  const float* __restrict__ bb,
                                                  float* __restrict__ out1,
                                                  int gb) {
    __shared__ float ws_[CH1 * 9];
    __shared__ float bs_[CH1];
    const int tid = threadIdx.x;
    for (int i = tid; i < CH1 * 9; i += 256) {
        int oc = i / 9;
        ws_[i] = w[i] * g[oc];
    }
    if (tid < CH1) bs_[tid] = cb[tid] * g[tid] + bb[tid];
    __syncthreads();

    int t = blockIdx.x * 256 + tid;
    if (t >= gb * H1 * W1) return;
    int lb = t / (H1 * W1);
    int r = t % (H1 * W1);
    int py = r / W1, px = r % W1;
    const float* fb = fused + (size_t)lb * EL_HEAT;

    float v[4][4];
    int y0 = 2 * py - 1, x0 = 2 * px - 1;
#pragma unroll
    for (int i = 0; i < 4; i++) {
#pragma unroll
        for (int j = 0; j < 4; j++) {
            int y = y0 + i, x = x0 + j;
            v[i][j] = (y >= 0 && y < IH && x >= 0 && x < IW) ? fb[(size_t)y * IW + x] : 0.0f;
        }
    }
    for (int oc = 0; oc < CH1; oc++) {
        float a00 = 0, a01 = 0, a10 = 0, a11 = 0;
        const float* wp = &ws_[oc * 9];
#pragma unroll
        for (int ky = 0; ky < 3; ky++) {
#pragma unroll
            for (int kx = 0; kx < 3; kx++) {
                float wv = wp[ky * 3 + kx];
                a00 += wv * v[ky][kx];
                a01 += wv * v[ky][kx + 1];
                a10 += wv * v[ky + 1][kx];
                a11 += wv * v[ky + 1][kx + 1];
            }
        }
        float bias = bs_[oc];
        a00 = fmaxf(a00 + bias, 0.0f);
        a01 = fmaxf(a01 + bias, 0.0f);
        a10 = fmaxf(a10 + bias, 0.0f);
        a11 = fmaxf(a11 + bias, 0.0f);
        float mx = fmaxf(fmaxf(a00, a01), fmaxf(a10, a11));
        out1[(((size_t)lb * CH1 + oc) * H1 + py) * W1 + px] = mx;
    }
}

// ---------------------------------------------------------------------------
// K4: conv2(32->64) + BN + relu + pool
// ---------------------------------------------------------------------------
__global__ __launch_bounds__(256) void conv2_pool(const float* __restrict__ in,
                                                  const float* __restrict__ w,
                                                  const float* __restrict__ cb,
                                                  const float* __restrict__ g,
                                                  const float* __restrict__ bb,
                                                  float* __restrict__ out) {
    __shared__ float ws_[8 * CH1 * 9];
    __shared__ float bs_[8];
    const int tid = threadIdx.x;
    const int ocg = blockIdx.y;
    const int lb = blockIdx.z;
    for (int i = tid; i < 8 * CH1 * 9; i += 256) {
        int o = i / (CH1 * 9);
        int rest = i % (CH1 * 9);
        int oc = ocg * 8 + o;
        ws_[i] = w[(size_t)oc * CH1 * 9 + rest] * g[oc];
    }
    if (tid < 8) {
        int oc = ocg * 8 + tid;
        bs_[tid] = cb[oc] * g[oc] + bb[oc];
    }
    __syncthreads();

    int pid = blockIdx.x * 256 + tid;
    if (pid >= PIX2) return;
    int py = pid / W2, px = pid % W2;
    float acc[8][4];
#pragma unroll
    for (int o = 0; o < 8; o++)
#pragma unroll
        for (int q = 0; q < 4; q++) acc[o][q] = 0.0f;

    int y0 = 2 * py - 1, x0 = 2 * px - 1;
    for (int ic = 0; ic < CH1; ic++) {
        float v[4][4];
        const float* ip = in + ((size_t)lb * CH1 + ic) * H1 * W1;
#pragma unroll
        for (int i = 0; i < 4; i++) {
#pragma unroll
            for (int j = 0; j < 4; j++) {
                int y = y0 + i, x = x0 + j;
                v[i][j] = (y >= 0 && y < H1 && x >= 0 && x < W1) ? ip[(size_t)y * W1 + x] : 0.0f;
            }
        }
#pragma unroll
        for (int o = 0; o < 8; o++) {
            const float* wp = &ws_[(o * CH1 + ic) * 9];
#pragma unroll
            for (int ky = 0; ky < 3; ky++) {
#pragma unroll
                for (int kx = 0; kx < 3; kx++) {
                    float wv = wp[ky * 3 + kx];
                    acc[o][0] += wv * v[ky][kx];
                    acc[o][1] += wv * v[ky][kx + 1];
                    acc[o][2] += wv * v[ky + 1][kx];
                    acc[o][3] += wv * v[ky + 1][kx + 1];
                }
            }
        }
    }
#pragma unroll
    for (int o = 0; o < 8; o++) {
        float bias = bs_[o];
        float a0 = fmaxf(acc[o][0] + bias, 0.0f);
        float a1 = fmaxf(acc[o][1] + bias, 0.0f);
        float a2 = fmaxf(acc[o][2] + bias, 0.0f);
        float a3 = fmaxf(acc[o][3] + bias, 0.0f);
        float mx = fmaxf(fmaxf(a0, a1), fmaxf(a2, a3));
        out[(((size_t)lb * CH2 + ocg * 8 + o) * H2 + py) * W2 + px] = mx;
    }
}

// ---------------------------------------------------------------------------
// Weight fold/transpose for MFMA convs: wT[tap][oc][ic] = bf16(w[oc][ic][tap]*g[oc])
// bfold[oc] = cb[oc]*g[oc] + bb[oc]
// ---------------------------------------------------------------------------
__global__ __launch_bounds__(256) void wfold_k(const float* __restrict__ w,
                                               const float* __restrict__ g,
                                               const float* __restrict__ cb,
                                               const float* __restrict__ bb,
                                               short* __restrict__ wT,
                                               float* __restrict__ bfold,
                                               int IC) {
    int i = blockIdx.x * 256 + threadIdx.x;
    int n = 9 * 128 * IC;
    if (i >= n) return;
    int tap = i / (128 * IC);
    int r = i % (128 * IC);
    int oc = r / IC;
    int ic = r % IC;
    float v = w[((size_t)oc * IC + ic) * 9 + tap] * g[oc];
    __hip_bfloat16 h = __float2bfloat16(v);
    wT[i] = *reinterpret_cast<short*>(&h);
    if (tap == 0 && ic == 0) bfold[oc] = cb[oc] * g[oc] + bb[oc];
}

// ---------------------------------------------------------------------------
// K5-K8: 3x3 'SAME' conv via bf16 MFMA implicit GEMM.
// Block: (xtile 0..5, row y 0..44, lb). 256 thr = 4 waves; wave w covers
// ocs [32w,32w+32) via two 16x16x32 accumulators. M = 16 pixels in the row.
// K-loop: ic-chunks of 32 x 9 taps. Input staged to LDS as bf16 with halo.
// MFMA layouts (HW-verified per guide): A[m=lane&15][k=quad*8+j],
// B^T[n=lane&15][k=quad*8+j], C: n=lane&15, m=quad*4+reg.
// ---------------------------------------------------------------------------
template <int IC, bool SIG>
__global__ __launch_bounds__(256) void conv3x3_mfma(const float* __restrict__ in,
                                                    const short* __restrict__ wT,
                                                    const float* __restrict__ bfold,
                                                    float* __restrict__ out) {
    const int xt = blockIdx.x;      // 0..5
    const int y  = blockIdx.y;      // 0..44
    const int lb = blockIdx.z;
    const int x0 = xt * 16;
    const int tid = threadIdx.x;
    const int wave = tid >> 6;
    const int lane = tid & 63;
    const int m = lane & 15;
    const int q = lane >> 4;

    constexpr int KC = 32;          // ic chunk
    constexpr int NCH = IC / KC;
    constexpr int AP = 40;          // padded ic stride (80B rows: 16B-aligned b128)
    __shared__ __align__(16) short tileA[3 * 18 * AP];   // 4320 B

    floatx4 acc0 = {0.f, 0.f, 0.f, 0.f};
    floatx4 acc1 = {0.f, 0.f, 0.f, 0.f};

    const float* inb = in + (size_t)lb * IC * PIX2;

    for (int c = 0; c < NCH; ++c) {
        const int ic0 = c * KC;
        // stage input tile [3 rows][18 x][32 ic] as bf16, zero-padded halo
        for (int e = tid; e < 3 * 18 * KC; e += 256) {
            int dy  = e / (18 * KC);
            int r   = e % (18 * KC);
            int icl = r / 18;
            int tx  = r % 18;
            int yin = y + dy - 1;
            int xin = x0 + tx - 1;
            float v = 0.0f;
            if (yin >= 0 && yin < H2 && xin >= 0 && xin < W2)
                v = inb[(size_t)(ic0 + icl) * PIX2 + yin * W2 + xin];
            __hip_bfloat16 h = __float2bfloat16(v);
            tileA[(dy * 18 + tx) * AP + icl] = *reinterpret_cast<short*>(&h);
        }
        __syncthreads();

        const int oc0 = wave * 32 + m;   // n-index for B frags / C cols
#pragma unroll
        for (int tap = 0; tap < 9; ++tap) {
            const int dy = tap / 3, dx = tap % 3;
            short8 af = *reinterpret_cast<const short8*>(
                &tileA[(dy * 18 + dx + m) * AP + q * 8]);
            const short* wt = wT + (size_t)tap * 128 * IC;
            short8 b0 = *reinterpret_cast<const short8*>(
                &wt[(size_t)oc0 * IC + ic0 + q * 8]);
            short8 b1 = *reinterpret_cast<const short8*>(
                &wt[(size_t)(oc0 + 16) * IC + ic0 + q * 8]);
            acc0 = __builtin_amdgcn_mfma_f32_16x16x32_bf16(af, b0, acc0, 0, 0, 0);
            acc1 = __builtin_amdgcn_mfma_f32_16x16x32_bf16(af, b1, acc1, 0, 0, 0);
        }
        __syncthreads();
    }

    // epilogue: C[m=q*4+reg (pixel), n=lane&15 (oc)]
    float* outb = out + (size_t)lb * 128 * PIX2;
    const int oc0 = wave * 32 + m;
    const float bias0 = bfold[oc0];
    const float bias1 = bfold[oc0 + 16];
#pragma unroll
    for (int r = 0; r < 4; ++r) {
        int x = x0 + q * 4 + r;
        if (x < W2) {
            float z0 = acc0[r] + bias0;
            float z1 = acc1[r] + bias1;
            if (SIG) {
                z0 = 1.0f / (1.0f + expf(-z0));
                z1 = 1.0f / (1.0f + expf(-z1));
            } else {
                z0 = fmaxf(z0, 0.0f);
                z1 = fmaxf(z1, 0.0f);
            }
            outb[(size_t)oc0 * PIX2 + y * W2 + x] = z0;
            outb[(size_t)(oc0 + 16) * PIX2 + y * W2 + x] = z1;
        }
    }
}

// ---------------------------------------------------------------------------
// K9: per-(local)batch min/max of p2 output
// ---------------------------------------------------------------------------
__global__ __launch_bounds__(256) void pminmax(const float* __restrict__ p,
                                               float* __restrict__ mm) {
    const int lb = blockIdx.x;
    const float* pb = p + (size_t)lb * EL_MAP3;
    float mn = INFINITY, mx = -INFINITY;
    for (int i = threadIdx.x; i < EL_MAP3; i += 256) {
        float v = pb[i];
        mn = fminf(mn, v);
        mx = fmaxf(mx, v);
    }
    __shared__ float rmn[256], rmx[256];
    rmn[threadIdx.x] = mn; rmx[threadIdx.x] = mx;
    __syncthreads();
    for (int s = 128; s > 0; s >>= 1) {
        if (threadIdx.x < s) {
            rmn[threadIdx.x] = fminf(rmn[threadIdx.x], rmn[threadIdx.x + s]);
            rmx[threadIdx.x] = fmaxf(rmx[threadIdx.x], rmx[threadIdx.x + s]);
        }
        __syncthreads();
    }
    if (threadIdx.x == 0) { mm[lb * 2] = rmn[0]; mm[lb * 2 + 1] = rmx[0]; }
}

// ---------------------------------------------------------------------------
// K10: p_map = sigmoid(10*((p-min)/max(max-min,1e-4) - 0.5))  (in place)
// ---------------------------------------------------------------------------
__global__ __launch_bounds__(256) void pmap_k(float* __restrict__ p,
                                              const float* __restrict__ mm,
                                              int n) {
    int i = blockIdx.x * 256 + threadIdx.x;
    if (i >= n) return;
    int lb = i / EL_MAP3;
    float mn = mm[lb * 2], mx = mm[lb * 2 + 1];
    float denom = fmaxf(mx - mn, 1e-4f);
    float v = (p[i] - mn) / denom;
    p[i] = 1.0f / (1.0f + expf(-10.0f * (v - 0.5f)));
}

// ---------------------------------------------------------------------------
// K11: p_x[lb,p,c] = (1/3690) * sum_hw pmap[lb,p,hw]*fx[lb,c,hw]
// ---------------------------------------------------------------------------
__global__ __launch_bounds__(256) void einsum_k(const float* __restrict__ pm,
                                                const float* __restrict__ fx,
                                                float* __restrict__ px) {
    const int lb = blockIdx.z;
    const int pt = blockIdx.y;
    const int ct = blockIdx.x;
    __shared__ float As[32][65], Bs[32][65];
    const int tid = threadIdx.x;
    const int ty = tid / 16, tx = tid % 16;
    float acc00 = 0, acc01 = 0, acc10 = 0, acc11 = 0;
    const float* A = pm + ((size_t)lb * CH3 + pt * 32) * PIX2;
    const float* Bp = fx + ((size_t)lb * CH3 + ct * 32) * PIX2;
    for (int kk = 0; kk < PIX2; kk += 64) {
        for (int l = tid; l < 2048; l += 256) {
            int row = l >> 6, k = l & 63;
            int gk = kk + k;
            float av = 0, bv = 0;
            if (gk < PIX2) {
                av = A[(size_t)row * PIX2 + gk];
                bv = Bp[(size_t)row * PIX2 + gk];
            }
            As[row][k] = av;
            Bs[row][k] = bv;
        }
        __syncthreads();
#pragma unroll
        for (int k = 0; k < 64; k++) {
            float a0 = As[2 * ty][k], a1 = As[2 * ty + 1][k];
            float b0 = Bs[2 * tx][k], b1 = Bs[2 * tx + 1][k];
            acc00 += a0 * b0; acc01 += a0 * b1;
            acc10 += a1 * b0; acc11 += a1 * b1;
        }
        __syncthreads();
    }
    const float inv = 1.0f / (float)PIX2;
    int p0 = pt * 32 + 2 * ty, c0 = ct * 32 + 2 * tx;
    px[((size_t)lb * CH3 + p0) * CH3 + c0] = acc00 * inv;
    px[((size_t)lb * CH3 + p0) * CH3 + c0 + 1] = acc01 * inv;
    px[((size_t)lb * CH3 + p0 + 1) * CH3 + c0] = acc10 * inv;
    px[((size_t)lb * CH3 + p0 + 1) * CH3 + c0 + 1] = acc11 * inv;
}

// ---------------------------------------------------------------------------
// K12: out[b0+lb,o] = sum_k px[lb,k]*fc_w[o,k] + fc_b[o]  (f32 output)
// ---------------------------------------------------------------------------
__global__ __launch_bounds__(256) void fc_k(const float* __restrict__ px,
                                            const float* __restrict__ w,
                                            const float* __restrict__ bias,
                                            float* __restrict__ out,
                                            int b0) {
    const int gw = blockIdx.x * 4 + (threadIdx.x >> 6);
    const int lane = threadIdx.x & 63;
    const int lb = gw >> 8;
    const int o = gw & 255;
    const float* xb = px + (size_t)lb * EL_PX;
    const float* wr = w + (size_t)o * EL_PX;
    float s = 0.0f;
    for (int k = lane; k < EL_PX; k += 64) s += xb[k] * wr[k];
#pragma unroll
    for (int off = 32; off > 0; off >>= 1) s += __shfl_down(s, off);
    if (lane == 0) out[(size_t)(b0 + lb) * 256 + o] = s + bias[o];
}

// ---------------------------------------------------------------------------
extern "C" void kernel_launch(void* const* d_in, const int* in_sizes, int n_in,
                              void* d_out, int out_size, void* d_ws, size_t ws_size,
                              hipStream_t stream) {
    const float* x_t   = (const float*)d_in[0];
    const float* image = (const float*)d_in[1];
    const float* c1_w  = (const float*)d_in[2];
    const float* c1_b  = (const float*)d_in[3];
    const float* bn1_g = (const float*)d_in[4];
    const float* bn1_b = (const float*)d_in[5];
    const float* c2_w  = (const float*)d_in[6];
    const float* c2_b  = (const float*)d_in[7];
    const float* bn2_g = (const float*)d_in[8];
    const float* bn2_b = (const float*)d_in[9];
    const float* a1_w  = (const float*)d_in[10];
    const float* a1_b  = (const float*)d_in[11];
    const float* abn1_g= (const float*)d_in[12];
    const float* abn1_b= (const float*)d_in[13];
    const float* a2_w  = (const float*)d_in[14];
    const float* a2_b  = (const float*)d_in[15];
    const float* abn2_g= (const float*)d_in[16];
    const float* abn2_b= (const float*)d_in[17];
    const float* p1_w  = (const float*)d_in[18];
    const float* p1_b  = (const float*)d_in[19];
    const float* pbn1_g= (const float*)d_in[20];
    const float* pbn1_b= (const float*)d_in[21];
    const float* p2_w  = (const float*)d_in[22];
    const float* p2_b  = (const float*)d_in[23];
    const float* pbn2_g= (const float*)d_in[24];
    const float* pbn2_b= (const float*)d_in[25];
    const float* fc_w  = (const float*)d_in[26];
    const float* fc_b  = (const float*)d_in[27];
    float* outp = (float*)d_out;

    // Fixed region first (aligned): folded bf16 weights + biases.
    float* ws = (float*)d_ws;
    short* wTa1 = (short*)ws;                       // WSH_A1
    short* wTa2 = wTa1 + WSH_A1;                    // WSH_A2
    short* wTp1 = wTa2 + WSH_A2;                    // WSH_A1
    short* wTp2 = wTp1 + WSH_A1;                    // WSH_A2
    float* bfa1 = ws + WSH_TOT / 2;                 // 128 each
    float* bfa2 = bfa1 + 128;
    float* bfp1 = bfa2 + 128;
    float* bfp2 = bfp1 + 128;
    float* dyn  = bfp2 + 128;
    const size_t fixed_floats = WSH_TOT / 2 + 512;

    // Largest batch-group whose f32 footprint fits ws_size.
    int GB = 32;
    while (GB > 1) {
        size_t need = ((size_t)GB * EL_PER_BATCH + fixed_floats + 256) * sizeof(float);
        if (need <= ws_size) break;
        GB >>= 1;
    }
    const int ngroups = NB / GB;

    float* heat  = dyn;                               // GB*EL_HEAT
    float* m     = heat + (size_t)GB * EL_HEAT;       // 64
    float* fused = m + 64;                            // GB*EL_HEAT
    float* out1  = fused + (size_t)GB * EL_HEAT;      // GB*EL_OUT1
    float* out2  = out1 + (size_t)GB * EL_OUT1;       // GB*EL_OUT2
    float* fbuf  = out2 + (size_t)GB * EL_OUT2;       // GB*EL_MAP3
    float* fx    = fbuf + (size_t)GB * EL_MAP3;       // GB*EL_MAP3
    float* pp1   = fx + (size_t)GB * EL_MAP3;         // GB*EL_MAP3
    float* pp2   = pp1 + (size_t)GB * EL_MAP3;        // GB*EL_MAP3
    float* pmm   = pp2 + (size_t)GB * EL_MAP3;        // 64
    float* px    = pmm + 64;                          // GB*EL_PX

    // Fold weights (once per launch; identical work every call)
    wfold_k<<<(9 * 128 * CH2 + 255) / 256, 256, 0, stream>>>(a1_w, abn1_g, a1_b, abn1_b, wTa1, bfa1, CH2);
    wfold_k<<<(9 * 128 * CH3 + 255) / 256, 256, 0, stream>>>(a2_w, abn2_g, a2_b, abn2_b, wTa2, bfa2, CH3);
    wfold_k<<<(9 * 128 * CH2 + 255) / 256, 256, 0, stream>>>(p1_w, pbn1_g, p1_b, pbn1_b, wTp1, bfp1, CH2);
    wfold_k<<<(9 * 128 * CH3 + 255) / 256, 256, 0, stream>>>(p2_w, pbn2_g, p2_b, pbn2_b, wTp2, bfp2, CH3);

    const int ptiles = (PIX2 + 255) / 256;   // 15

    for (int gidx = 0; gidx < ngroups; ++gidx) {
        const int b0 = gidx * GB;
        // K1: LDS strip scatter (covers every element -> no pre-zero)
        heat_scatter<<<dim3(6, GB), 256, 0, stream>>>(x_t, heat, b0);
        // K2: per-batch max
        heat_max<<<GB, 256, 0, stream>>>(heat, m);
        // K2b: fused
        {
            int n = GB * EL_HEAT;
            fuse_k<<<(n + 255) / 256, 256, 0, stream>>>(heat, image, m, fused, b0, GB);
        }
        // K3: conv1+pool
        conv1_pool<<<(GB * H1 * W1 + 255) / 256, 256, 0, stream>>>(
            fused, c1_w, c1_b, bn1_g, bn1_b, out1, GB);
        // K4: conv2+pool
        conv2_pool<<<dim3(ptiles, CH2 / 8, GB), 256, 0, stream>>>(
            out1, c2_w, c2_b, bn2_g, bn2_b, out2);
        // K5-K8: MFMA convs
        conv3x3_mfma<CH2, false><<<dim3(6, H2, GB), 256, 0, stream>>>(out2, wTa1, bfa1, fbuf);
        conv3x3_mfma<CH3, true ><<<dim3(6, H2, GB), 256, 0, stream>>>(fbuf, wTa2, bfa2, fx);
        conv3x3_mfma<CH2, false><<<dim3(6, H2, GB), 256, 0, stream>>>(out2, wTp1, bfp1, pp1);
        conv3x3_mfma<CH3, false><<<dim3(6, H2, GB), 256, 0, stream>>>(pp1, wTp2, bfp2, pp2);
        // K9: min/max
        pminmax<<<GB, 256, 0, stream>>>(pp2, pmm);
        // K10: sigmoid map (in place)
        {
            int n = GB * EL_MAP3;
            pmap_k<<<(n + 255) / 256, 256, 0, stream>>>(pp2, pmm, n);
        }
        // K11: einsum -> px
        einsum_k<<<dim3(4, 4, GB), 256, 0, stream>>>(pp2, fx, px);
        // K12: FC -> out (f32)
        fc_k<<<GB * 64, 256, 0, stream>>>(px, fc_w, fc_b, outp, b0);
    }
}

// Round 7
// 3100.778 us; speedup vs baseline: 2.5792x; 1.4035x over previous
//
#include <hip/hip_runtime.h>
#include <hip/hip_bf16.h>

// Problem constants
#define NB 32
#define NT 1024
#define IH 180
#define IW 330
#define KSZ 37
#define H1 90
#define W1 165
#define H2 45
#define W2 82
#define PIX2 (H2*W2)          // 3690
#define CH1 32
#define CH2 64
#define CH3 128

// Per-batch f32 element counts
#define EL_HEAT (IH*IW)           // 59,400
#define EL_OUT1 (CH1*H1*W1)       // 475,200
#define EL_OUT2 (CH2*PIX2)        // 236,160
#define EL_MAP3 (CH3*PIX2)        // 472,320
#define EL_PX   (CH3*CH3)         // 16,384
#define EL_PER_BATCH (2*EL_HEAT + EL_OUT1 + EL_OUT2 + 4*EL_MAP3 + EL_PX) // 2,735,824

// folded-weight sizes (bf16 shorts): wT[tap][oc=128][ic]
#define WSH_A1 (9*128*64)         // 73,728
#define WSH_A2 (9*128*128)        // 147,456
#define WSH_TOT (2*WSH_A1 + 2*WSH_A2)  // 442,368 shorts = 221,184 float slots

typedef __attribute__((ext_vector_type(8))) short short8;   // 8 bf16 = 4 VGPRs
typedef __attribute__((ext_vector_type(4))) float floatx4;

// ---------------------------------------------------------------------------
// K_init: init m (heat max, >=0 -> 0 bits) and pmm (min=+inf, max=0 bits)
// ---------------------------------------------------------------------------
__global__ __launch_bounds__(256) void mm_init(unsigned* __restrict__ m_bits,
                                               unsigned* __restrict__ pmm_bits) {
    int i = threadIdx.x;
    if (i < 64) {
        m_bits[i] = 0u;
        pmm_bits[2 * i]     = 0x7F800000u;   // +inf (min slot)
        pmm_bits[2 * i + 1] = 0u;            // 0.0  (max slot)
    }
}

// ---------------------------------------------------------------------------
// K1: heatmap scatter, wave-parallel. One block per (strip, local batch);
// one WAVE per point, lanes = patch columns (lane < nc). The per-lane
// dependency chain is <=37 LDS atomics (vs 1369 scalar before).
// ---------------------------------------------------------------------------
__global__ __launch_bounds__(256) void heat_scatter(const float* __restrict__ x_t,
                                                    float* __restrict__ heat,
                                                    int b0) {
    const int strip = blockIdx.x;          // 6 strips of 64 cols
    const int lb = blockIdx.y;
    const int b = b0 + lb;
    const int c0 = strip * 64;
    const int cw = min(64, IW - c0);
    __shared__ float lds[IH * 64];
    __shared__ float k1n[64];              // cols 37..63 are zero
    const int tid = threadIdx.x;

    if (tid < 64) {
        float v = 0.0f;
        if (tid < KSZ) {
            float ax = (float)tid - 18.0f;
            v = expf(-ax * ax / 18.0f);    // 2*sigma^2 = 18
        }
        k1n[tid] = v;
    }
    for (int i = tid; i < IH * 64; i += 256) lds[i] = 0.0f;
    __syncthreads();
    if (tid == 0) {
        float s = 0.0f;
        for (int i = 0; i < KSZ; i++) s += k1n[i];
        float inv = 1.0f / s;
        for (int i = 0; i < KSZ; i++) k1n[i] *= inv;
    }
    __syncthreads();

    const int wave = tid >> 6;
    const int lane = tid & 63;
    const float kc = k1n[lane];            // column weight for this lane

    for (int p = wave; p < NT; p += 4) {
        float x = x_t[(size_t)(b * NT + p) * 2 + 0];
        float y = x_t[(size_t)(b * NT + p) * 2 + 1];
        if (isnan(x) || isnan(y)) continue;
        int xp = IH - (int)((x - 30.0f) * 180.0f);
        int yp = (int)((y - 120.0f) * 165.0f);
        int xs = min(max(xp - 18, 0), IH - 36);
        int xe = min(max(xp + 18, 0), IH);
        int ys = min(max(yp - 18, 0), IW - 36);
        int ye = min(max(yp + 18, 0), IW);
        int nr = xe - xs, nc = ye - ys;
        if (nr <= 0 || nc <= 0) continue;
        int cbeg = max(ys, c0);
        int cend = min(ys + nc, c0 + cw);
        if (cbeg >= cend) continue;        // wave-uniform skip
        int col = ys + lane;
        bool act = (lane < nc) && (col >= c0) && (col < c0 + cw);
        if (act) {
            int off = col - c0;
            for (int r = 0; r < nr; r++) {
                atomicAdd(&lds[(xs + r) * 64 + off], k1n[r] * kc);
            }
        }
    }
    __syncthreads();
    for (int i = tid; i < IH * cw; i += 256) {
        int row = i / cw, col = i % cw;
        heat[((size_t)lb * IH + row) * IW + c0 + col] = lds[row * 64 + col];
    }
}

// ---------------------------------------------------------------------------
// K2: per-(local)batch max of heat — multi-block + unsigned atomicMax
// (heat >= 0 so uint order == float order)
// ---------------------------------------------------------------------------
__global__ __launch_bounds__(256) void heat_max(const float* __restrict__ heat,
                                                unsigned* __restrict__ m_bits) {
    const int chunk = blockIdx.x;          // 0..3
    const int lb = blockIdx.y;
    const int n0 = chunk * (EL_HEAT / 4);
    const int n1 = (chunk == 3) ? EL_HEAT : n0 + (EL_HEAT / 4);
    const float* hb = heat + (size_t)lb * EL_HEAT;
    float mx = 0.0f;
    for (int i = n0 + threadIdx.x; i < n1; i += 256) mx = fmaxf(mx, hb[i]);
    __shared__ float red[256];
    red[threadIdx.x] = mx;
    __syncthreads();
    for (int s = 128; s > 0; s >>= 1) {
        if (threadIdx.x < s) red[threadIdx.x] = fmaxf(red[threadIdx.x], red[threadIdx.x + s]);
        __syncthreads();
    }
    if (threadIdx.x == 0) atomicMax(&m_bits[lb], __float_as_uint(red[0]));
}

// ---------------------------------------------------------------------------
// K2b: fused = 0.7*(heat/(m+1e-10)) + 0.3*image
// ---------------------------------------------------------------------------
__global__ __launch_bounds__(256) void fuse_k(const float* __restrict__ heat,
                                              const float* __restrict__ image,
                                              const float* __restrict__ m,
                                              float* __restrict__ fused,
                                              int b0, int gb) {
    int t = blockIdx.x * 256 + threadIdx.x;
    if (t >= gb * EL_HEAT) return;
    int lb = t / EL_HEAT;
    int r  = t % EL_HEAT;
    float hn = heat[(size_t)lb * EL_HEAT + r] / (m[lb] + 1e-10f);
    float iv = image[(size_t)(b0 + lb) * EL_HEAT + r];
    fused[(size_t)lb * EL_HEAT + r] = 0.7f * hn + 0.3f * iv;
}

// ---------------------------------------------------------------------------
// K3: conv1(1->32) + BN + relu + pool
// ---------------------------------------------------------------------------
__global__ __launch_bounds__(256) void conv1_pool(const float* __restrict__ fused,
                                                  const float* __restrict__ w,
                                                  const float* __restrict__ cb,
                                                  const float* __restrict__ g,
                                                  const float* __restrict__ bb,
                                                  float* __restrict__ out1,
                                                  int gb) {
    __shared__ float ws_[CH1 * 9];
    __shared__ float bs_[CH1];
    const int tid = threadIdx.x;
    for (int i = tid; i < CH1 * 9; i += 256) {
        int oc = i / 9;
        ws_[i] = w[i] * g[oc];
    }
    if (tid < CH1) bs_[tid] = cb[tid] * g[tid] + bb[tid];
    __syncthreads();

    int t = blockIdx.x * 256 + tid;
    if (t >= gb * H1 * W1) return;
    int lb = t / (H1 * W1);
    int r = t % (H1 * W1);
    int py = r / W1, px = r % W1;
    const float* fb = fused + (size_t)lb * EL_HEAT;

    float v[4][4];
    int y0 = 2 * py - 1, x0 = 2 * px - 1;
#pragma unroll
    for (int i = 0; i < 4; i++) {
#pragma unroll
        for (int j = 0; j < 4; j++) {
            int y = y0 + i, x = x0 + j;
            v[i][j] = (y >= 0 && y < IH && x >= 0 && x < IW) ? fb[(size_t)y * IW + x] : 0.0f;
        }
    }
    for (int oc = 0; oc < CH1; oc++) {
        float a00 = 0, a01 = 0, a10 = 0, a11 = 0;
        const float* wp = &ws_[oc * 9];
#pragma unroll
        for (int ky = 0; ky < 3; ky++) {
#pragma unroll
            for (int kx = 0; kx < 3; kx++) {
                float wv = wp[ky * 3 + kx];
                a00 += wv * v[ky][kx];
                a01 += wv * v[ky][kx + 1];
                a10 += wv * v[ky + 1][kx];
                a11 += wv * v[ky + 1][kx + 1];
            }
        }
        float bias = bs_[oc];
        a00 = fmaxf(a00 + bias, 0.0f);
        a01 = fmaxf(a01 + bias, 0.0f);
        a10 = fmaxf(a10 + bias, 0.0f);
        a11 = fmaxf(a11 + bias, 0.0f);
        float mx = fmaxf(fmaxf(a00, a01), fmaxf(a10, a11));
        out1[(((size_t)lb * CH1 + oc) * H1 + py) * W1 + px] = mx;
    }
}

// ---------------------------------------------------------------------------
// K4: conv2(32->64) + BN + relu + pool
// ---------------------------------------------------------------------------
__global__ __launch_bounds__(256) void conv2_pool(const float* __restrict__ in,
                                                  const float* __restrict__ w,
                                                  const float* __restrict__ cb,
                                                  const float* __restrict__ g,
                                                  const float* __restrict__ bb,
                                                  float* __restrict__ out) {
    __shared__ float ws_[8 * CH1 * 9];
    __shared__ float bs_[8];
    const int tid = threadIdx.x;
    const int ocg = blockIdx.y;
    const int lb = blockIdx.z;
    for (int i = tid; i < 8 * CH1 * 9; i += 256) {
        int o = i / (CH1 * 9);
        int rest = i % (CH1 * 9);
        int oc = ocg * 8 + o;
        ws_[i] = w[(size_t)oc * CH1 * 9 + rest] * g[oc];
    }
    if (tid < 8) {
        int oc = ocg * 8 + tid;
        bs_[tid] = cb[oc] * g[oc] + bb[oc];
    }
    __syncthreads();

    int pid = blockIdx.x * 256 + tid;
    if (pid >= PIX2) return;
    int py = pid / W2, px = pid % W2;
    float acc[8][4];
#pragma unroll
    for (int o = 0; o < 8; o++)
#pragma unroll
        for (int q = 0; q < 4; q++) acc[o][q] = 0.0f;

    int y0 = 2 * py - 1, x0 = 2 * px - 1;
    for (int ic = 0; ic < CH1; ic++) {
        float v[4][4];
        const float* ip = in + ((size_t)lb * CH1 + ic) * H1 * W1;
#pragma unroll
        for (int i = 0; i < 4; i++) {
#pragma unroll
            for (int j = 0; j < 4; j++) {
                int y = y0 + i, x = x0 + j;
                v[i][j] = (y >= 0 && y < H1 && x >= 0 && x < W1) ? ip[(size_t)y * W1 + x] : 0.0f;
            }
        }
#pragma unroll
        for (int o = 0; o < 8; o++) {
            const float* wp = &ws_[(o * CH1 + ic) * 9];
#pragma unroll
            for (int ky = 0; ky < 3; ky++) {
#pragma unroll
                for (int kx = 0; kx < 3; kx++) {
                    float wv = wp[ky * 3 + kx];
                    acc[o][0] += wv * v[ky][kx];
                    acc[o][1] += wv * v[ky][kx + 1];
                    acc[o][2] += wv * v[ky + 1][kx];
                    acc[o][3] += wv * v[ky + 1][kx + 1];
                }
            }
        }
    }
#pragma unroll
    for (int o = 0; o < 8; o++) {
        float bias = bs_[o];
        float a0 = fmaxf(acc[o][0] + bias, 0.0f);
        float a1 = fmaxf(acc[o][1] + bias, 0.0f);
        float a2 = fmaxf(acc[o][2] + bias, 0.0f);
        float a3 = fmaxf(acc[o][3] + bias, 0.0f);
        float mx = fmaxf(fmaxf(a0, a1), fmaxf(a2, a3));
        out[(((size_t)lb * CH2 + ocg * 8 + o) * H2 + py) * W2 + px] = mx;
    }
}

// ---------------------------------------------------------------------------
// Weight fold/transpose for MFMA convs: wT[tap][oc][ic] = bf16(w[oc][ic][tap]*g[oc])
// ---------------------------------------------------------------------------
__global__ __launch_bounds__(256) void wfold_k(const float* __restrict__ w,
                                               const float* __restrict__ g,
                                               const float* __restrict__ cb,
                                               const float* __restrict__ bb,
                                               short* __restrict__ wT,
                                               float* __restrict__ bfold,
                                               int IC) {
    int i = blockIdx.x * 256 + threadIdx.x;
    int n = 9 * 128 * IC;
    if (i >= n) return;
    int tap = i / (128 * IC);
    int r = i % (128 * IC);
    int oc = r / IC;
    int ic = r % IC;
    float v = w[((size_t)oc * IC + ic) * 9 + tap] * g[oc];
    __hip_bfloat16 h = __float2bfloat16(v);
    wT[i] = *reinterpret_cast<short*>(&h);
    if (tap == 0 && ic == 0) bfold[oc] = cb[oc] * g[oc] + bb[oc];
}

// ---------------------------------------------------------------------------
// K5-K8: 3x3 'SAME' conv via bf16 MFMA implicit GEMM.
// ---------------------------------------------------------------------------
template <int IC, bool SIG>
__global__ __launch_bounds__(256) void conv3x3_mfma(const float* __restrict__ in,
                                                    const short* __restrict__ wT,
                                                    const float* __restrict__ bfold,
                                                    float* __restrict__ out) {
    const int xt = blockIdx.x;      // 0..5
    const int y  = blockIdx.y;      // 0..44
    const int lb = blockIdx.z;
    const int x0 = xt * 16;
    const int tid = threadIdx.x;
    const int wave = tid >> 6;
    const int lane = tid & 63;
    const int m = lane & 15;
    const int q = lane >> 4;

    constexpr int KC = 32;          // ic chunk
    constexpr int NCH = IC / KC;
    constexpr int AP = 40;          // padded ic stride
    __shared__ __align__(16) short tileA[3 * 18 * AP];

    floatx4 acc0 = {0.f, 0.f, 0.f, 0.f};
    floatx4 acc1 = {0.f, 0.f, 0.f, 0.f};

    const float* inb = in + (size_t)lb * IC * PIX2;

    for (int c = 0; c < NCH; ++c) {
        const int ic0 = c * KC;
        for (int e = tid; e < 3 * 18 * KC; e += 256) {
            int dy  = e / (18 * KC);
            int r   = e % (18 * KC);
            int icl = r / 18;
            int tx  = r % 18;
            int yin = y + dy - 1;
            int xin = x0 + tx - 1;
            float v = 0.0f;
            if (yin >= 0 && yin < H2 && xin >= 0 && xin < W2)
                v = inb[(size_t)(ic0 + icl) * PIX2 + yin * W2 + xin];
            __hip_bfloat16 h = __float2bfloat16(v);
            tileA[(dy * 18 + tx) * AP + icl] = *reinterpret_cast<short*>(&h);
        }
        __syncthreads();

        const int oc0 = wave * 32 + m;
#pragma unroll
        for (int tap = 0; tap < 9; ++tap) {
            const int dy = tap / 3, dx = tap % 3;
            short8 af = *reinterpret_cast<const short8*>(
                &tileA[(dy * 18 + dx + m) * AP + q * 8]);
            const short* wt = wT + (size_t)tap * 128 * IC;
            short8 b0 = *reinterpret_cast<const short8*>(
                &wt[(size_t)oc0 * IC + ic0 + q * 8]);
            short8 b1 = *reinterpret_cast<const short8*>(
                &wt[(size_t)(oc0 + 16) * IC + ic0 + q * 8]);
            acc0 = __builtin_amdgcn_mfma_f32_16x16x32_bf16(af, b0, acc0, 0, 0, 0);
            acc1 = __builtin_amdgcn_mfma_f32_16x16x32_bf16(af, b1, acc1, 0, 0, 0);
        }
        __syncthreads();
    }

    float* outb = out + (size_t)lb * 128 * PIX2;
    const int oc0 = wave * 32 + m;
    const float bias0 = bfold[oc0];
    const float bias1 = bfold[oc0 + 16];
#pragma unroll
    for (int r = 0; r < 4; ++r) {
        int x = x0 + q * 4 + r;
        if (x < W2) {
            float z0 = acc0[r] + bias0;
            float z1 = acc1[r] + bias1;
            if (SIG) {
                z0 = 1.0f / (1.0f + expf(-z0));
                z1 = 1.0f / (1.0f + expf(-z1));
            } else {
                z0 = fmaxf(z0, 0.0f);
                z1 = fmaxf(z1, 0.0f);
            }
            outb[(size_t)oc0 * PIX2 + y * W2 + x] = z0;
            outb[(size_t)(oc0 + 16) * PIX2 + y * W2 + x] = z1;
        }
    }
}

// ---------------------------------------------------------------------------
// K9: per-(local)batch min/max of p2 — multi-block + unsigned atomics
// (p2 is relu output >= 0)
// ---------------------------------------------------------------------------
__global__ __launch_bounds__(256) void pminmax(const float* __restrict__ p,
                                               unsigned* __restrict__ pmm_bits) {
    const int chunk = blockIdx.x;          // 0..31
    const int lb = blockIdx.y;
    const int n0 = chunk * (EL_MAP3 / 32);
    const int n1 = (chunk == 31) ? EL_MAP3 : n0 + (EL_MAP3 / 32);
    const float* pb = p + (size_t)lb * EL_MAP3;
    float mn = INFINITY, mx = 0.0f;
    for (int i = n0 + threadIdx.x; i < n1; i += 256) {
        float v = pb[i];
        mn = fminf(mn, v);
        mx = fmaxf(mx, v);
    }
    __shared__ float rmn[256], rmx[256];
    rmn[threadIdx.x] = mn; rmx[threadIdx.x] = mx;
    __syncthreads();
    for (int s = 128; s > 0; s >>= 1) {
        if (threadIdx.x < s) {
            rmn[threadIdx.x] = fminf(rmn[threadIdx.x], rmn[threadIdx.x + s]);
            rmx[threadIdx.x] = fmaxf(rmx[threadIdx.x], rmx[threadIdx.x + s]);
        }
        __syncthreads();
    }
    if (threadIdx.x == 0) {
        atomicMin(&pmm_bits[lb * 2],     __float_as_uint(rmn[0]));
        atomicMax(&pmm_bits[lb * 2 + 1], __float_as_uint(rmx[0]));
    }
}

// ---------------------------------------------------------------------------
// K10: p_map = sigmoid(10*((p-min)/max(max-min,1e-4) - 0.5))  (in place)
// ---------------------------------------------------------------------------
__global__ __launch_bounds__(256) void pmap_k(float* __restrict__ p,
                                              const float* __restrict__ mm,
                                              int n) {
    int i = blockIdx.x * 256 + threadIdx.x;
    if (i >= n) return;
    int lb = i / EL_MAP3;
    float mn = mm[lb * 2], mx = mm[lb * 2 + 1];
    float denom = fmaxf(mx - mn, 1e-4f);
    float v = (p[i] - mn) / denom;
    p[i] = 1.0f / (1.0f + expf(-10.0f * (v - 0.5f)));
}

// ---------------------------------------------------------------------------
// K11: p_x[lb,p,c] = (1/3690) * sum_hw pmap[lb,p,hw]*fx[lb,c,hw]
// ---------------------------------------------------------------------------
__global__ __launch_bounds__(256) void einsum_k(const float* __restrict__ pm,
                                                const float* __restrict__ fx,
                                                float* __restrict__ px) {
    const int lb = blockIdx.z;
    const int pt = blockIdx.y;
    const int ct = blockIdx.x;
    __shared__ float As[32][65], Bs[32][65];
    const int tid = threadIdx.x;
    const int ty = tid / 16, tx = tid % 16;
    float acc00 = 0, acc01 = 0, acc10 = 0, acc11 = 0;
    const float* A = pm + ((size_t)lb * CH3 + pt * 32) * PIX2;
    const float* Bp = fx + ((size_t)lb * CH3 + ct * 32) * PIX2;
    for (int kk = 0; kk < PIX2; kk += 64) {
        for (int l = tid; l < 2048; l += 256) {
            int row = l >> 6, k = l & 63;
            int gk = kk + k;
            float av = 0, bv = 0;
            if (gk < PIX2) {
                av = A[(size_t)row * PIX2 + gk];
                bv = Bp[(size_t)row * PIX2 + gk];
            }
            As[row][k] = av;
            Bs[row][k] = bv;
        }
        __syncthreads();
#pragma unroll
        for (int k = 0; k < 64; k++) {
            float a0 = As[2 * ty][k], a1 = As[2 * ty + 1][k];
            float b0 = Bs[2 * tx][k], b1 = Bs[2 * tx + 1][k];
            acc00 += a0 * b0; acc01 += a0 * b1;
            acc10 += a1 * b0; acc11 += a1 * b1;
        }
        __syncthreads();
    }
    const float inv = 1.0f / (float)PIX2;
    int p0 = pt * 32 + 2 * ty, c0 = ct * 32 + 2 * tx;
    px[((size_t)lb * CH3 + p0) * CH3 + c0] = acc00 * inv;
    px[((size_t)lb * CH3 + p0) * CH3 + c0 + 1] = acc01 * inv;
    px[((size_t)lb * CH3 + p0 + 1) * CH3 + c0] = acc10 * inv;
    px[((size_t)lb * CH3 + p0 + 1) * CH3 + c0 + 1] = acc11 * inv;
}

// ---------------------------------------------------------------------------
// K12: out[b0+lb,o] = sum_k px[lb,k]*fc_w[o,k] + fc_b[o]  (f32 output)
// ---------------------------------------------------------------------------
__global__ __launch_bounds__(256) void fc_k(const float* __restrict__ px,
                                            const float* __restrict__ w,
                                            const float* __restrict__ bias,
                                            float* __restrict__ out,
                                            int b0) {
    const int gw = blockIdx.x * 4 + (threadIdx.x >> 6);
    const int lane = threadIdx.x & 63;
    const int lb = gw >> 8;
    const int o = gw & 255;
    const float* xb = px + (size_t)lb * EL_PX;
    const float* wr = w + (size_t)o * EL_PX;
    float s = 0.0f;
    for (int k = lane; k < EL_PX; k += 64) s += xb[k] * wr[k];
#pragma unroll
    for (int off = 32; off > 0; off >>= 1) s += __shfl_down(s, off);
    if (lane == 0) out[(size_t)(b0 + lb) * 256 + o] = s + bias[o];
}

// ---------------------------------------------------------------------------
extern "C" void kernel_launch(void* const* d_in, const int* in_sizes, int n_in,
                              void* d_out, int out_size, void* d_ws, size_t ws_size,
                              hipStream_t stream) {
    const float* x_t   = (const float*)d_in[0];
    const float* image = (const float*)d_in[1];
    const float* c1_w  = (const float*)d_in[2];
    const float* c1_b  = (const float*)d_in[3];
    const float* bn1_g = (const float*)d_in[4];
    const float* bn1_b = (const float*)d_in[5];
    const float* c2_w  = (const float*)d_in[6];
    const float* c2_b  = (const float*)d_in[7];
    const float* bn2_g = (const float*)d_in[8];
    const float* bn2_b = (const float*)d_in[9];
    const float* a1_w  = (const float*)d_in[10];
    const float* a1_b  = (const float*)d_in[11];
    const float* abn1_g= (const float*)d_in[12];
    const float* abn1_b= (const float*)d_in[13];
    const float* a2_w  = (const float*)d_in[14];
    const float* a2_b  = (const float*)d_in[15];
    const float* abn2_g= (const float*)d_in[16];
    const float* abn2_b= (const float*)d_in[17];
    const float* p1_w  = (const float*)d_in[18];
    const float* p1_b  = (const float*)d_in[19];
    const float* pbn1_g= (const float*)d_in[20];
    const float* pbn1_b= (const float*)d_in[21];
    const float* p2_w  = (const float*)d_in[22];
    const float* p2_b  = (const float*)d_in[23];
    const float* pbn2_g= (const float*)d_in[24];
    const float* pbn2_b= (const float*)d_in[25];
    const float* fc_w  = (const float*)d_in[26];
    const float* fc_b  = (const float*)d_in[27];
    float* outp = (float*)d_out;

    // Fixed region first: folded bf16 weights + biases.
    float* ws = (float*)d_ws;
    short* wTa1 = (short*)ws;                       // WSH_A1
    short* wTa2 = wTa1 + WSH_A1;                    // WSH_A2
    short* wTp1 = wTa2 + WSH_A2;                    // WSH_A1
    short* wTp2 = wTp1 + WSH_A1;                    // WSH_A2
    float* bfa1 = ws + WSH_TOT / 2;                 // 128 each
    float* bfa2 = bfa1 + 128;
    float* bfp1 = bfa2 + 128;
    float* bfp2 = bfp1 + 128;
    float* dyn  = bfp2 + 128;
    const size_t fixed_floats = WSH_TOT / 2 + 512;

    int GB = 32;
    while (GB > 1) {
        size_t need = ((size_t)GB * EL_PER_BATCH + fixed_floats + 256) * sizeof(float);
        if (need <= ws_size) break;
        GB >>= 1;
    }
    const int ngroups = NB / GB;

    float* heat  = dyn;                               // GB*EL_HEAT
    float* m     = heat + (size_t)GB * EL_HEAT;       // 64
    float* fused = m + 64;                            // GB*EL_HEAT
    float* out1  = fused + (size_t)GB * EL_HEAT;      // GB*EL_OUT1
    float* out2  = out1 + (size_t)GB * EL_OUT1;       // GB*EL_OUT2
    float* fbuf  = out2 + (size_t)GB * EL_OUT2;       // GB*EL_MAP3
    float* fx    = fbuf + (size_t)GB * EL_MAP3;       // GB*EL_MAP3
    float* pp1   = fx + (size_t)GB * EL_MAP3;         // GB*EL_MAP3
    float* pp2   = pp1 + (size_t)GB * EL_MAP3;        // GB*EL_MAP3
    float* pmm   = pp2 + (size_t)GB * EL_MAP3;        // 64*2
    float* px    = pmm + 128;                         // GB*EL_PX

    // Fold weights (once per launch)
    wfold_k<<<(9 * 128 * CH2 + 255) / 256, 256, 0, stream>>>(a1_w, abn1_g, a1_b, abn1_b, wTa1, bfa1, CH2);
    wfold_k<<<(9 * 128 * CH3 + 255) / 256, 256, 0, stream>>>(a2_w, abn2_g, a2_b, abn2_b, wTa2, bfa2, CH3);
    wfold_k<<<(9 * 128 * CH2 + 255) / 256, 256, 0, stream>>>(p1_w, pbn1_g, p1_b, pbn1_b, wTp1, bfp1, CH2);
    wfold_k<<<(9 * 128 * CH3 + 255) / 256, 256, 0, stream>>>(p2_w, pbn2_g, p2_b, pbn2_b, wTp2, bfp2, CH3);

    const int ptiles = (PIX2 + 255) / 256;   // 15

    for (int gidx = 0; gidx < ngroups; ++gidx) {
        const int b0 = gidx * GB;
        // init m / pmm atomic targets
        mm_init<<<1, 256, 0, stream>>>((unsigned*)m, (unsigned*)pmm);
        // K1: wave-parallel LDS strip scatter
        heat_scatter<<<dim3(6, GB), 256, 0, stream>>>(x_t, heat, b0);
        // K2: per-batch max (multi-block atomic)
        heat_max<<<dim3(4, GB), 256, 0, stream>>>(heat, (unsigned*)m);
        // K2b: fused
        {
            int n = GB * EL_HEAT;
            fuse_k<<<(n + 255) / 256, 256, 0, stream>>>(heat, image, m, fused, b0, GB);
        }
        // K3: conv1+pool
        conv1_pool<<<(GB * H1 * W1 + 255) / 256, 256, 0, stream>>>(
            fused, c1_w, c1_b, bn1_g, bn1_b, out1, GB);
        // K4: conv2+pool
        conv2_pool<<<dim3(ptiles, CH2 / 8, GB), 256, 0, stream>>>(
            out1, c2_w, c2_b, bn2_g, bn2_b, out2);
        // K5-K8: MFMA convs
        conv3x3_mfma<CH2, false><<<dim3(6, H2, GB), 256, 0, stream>>>(out2, wTa1, bfa1, fbuf);
        conv3x3_mfma<CH3, true ><<<dim3(6, H2, GB), 256, 0, stream>>>(fbuf, wTa2, bfa2, fx);
        conv3x3_mfma<CH2, false><<<dim3(6, H2, GB), 256, 0, stream>>>(out2, wTp1, bfp1, pp1);
        conv3x3_mfma<CH3, false><<<dim3(6, H2, GB), 256, 0, stream>>>(pp1, wTp2, bfp2, pp2);
        // K9: min/max (multi-block atomic)
        pminmax<<<dim3(32, GB), 256, 0, stream>>>(pp2, (unsigned*)pmm);
        // K10: sigmoid map (in place)
        {
            int n = GB * EL_MAP3;
            pmap_k<<<(n + 255) / 256, 256, 0, stream>>>(pp2, pmm, n);
        }
        // K11: einsum -> px
        einsum_k<<<dim3(4, 4, GB), 256, 0, stream>>>(pp2, fx, px);
        // K12: FC -> out (f32)
        fc_k<<<GB * 64, 256, 0, stream>>>(px, fc_w, fc_b, outp, b0);
    }
}

// Round 8
// 1973.769 us; speedup vs baseline: 4.0519x; 1.5710x over previous
//
#include <hip/hip_runtime.h>
#include <hip/hip_bf16.h>

// Problem constants
#define NB 32
#define NT 1024
#define IH 180
#define IW 330
#define KSZ 37
#define H1 90
#define W1 165
#define H2 45
#define W2 82
#define PIX2 (H2*W2)          // 3690
#define CH1 32
#define CH2 64
#define CH3 128

// Per-batch f32 element counts
#define EL_HEAT (IH*IW)           // 59,400
#define EL_OUT1 (CH1*H1*W1)       // 475,200  (also hosts pp1: EL_MAP3 < EL_OUT1)
#define EL_OUT2 (CH2*PIX2)        // 236,160
#define EL_MAP3 (CH3*PIX2)        // 472,320
#define EL_PX   (CH3*CH3)         // 16,384
// overlay plan: B=EL_OUT1 hosts out1 then pp1; D=EL_MAP3 hosts fbuf then pp2
#define EL_PER_BATCH (EL_HEAT + EL_OUT1 + EL_OUT2 + 2*EL_MAP3 + EL_PX) // 1,731,784

// folded-weight sizes (bf16 shorts): wT[tap][oc=128][ic]
#define WSH_A1 (9*128*64)         // 73,728
#define WSH_A2 (9*128*128)        // 147,456
#define WSH_TOT (2*WSH_A1 + 2*WSH_A2)  // 442,368 shorts

typedef __attribute__((ext_vector_type(8))) short short8;   // 8 bf16
typedef __attribute__((ext_vector_type(4))) float floatx4;

__device__ __forceinline__ short f2bf(float v) {
    __hip_bfloat16 h = __float2bfloat16(v);
    return *reinterpret_cast<short*>(&h);
}

// ---------------------------------------------------------------------------
// zero kernel
// ---------------------------------------------------------------------------
__global__ __launch_bounds__(256) void zero_k(float* __restrict__ p, int n) {
    int i = blockIdx.x * 256 + threadIdx.x;
    if (i < n) p[i] = 0.0f;
}

// ---------------------------------------------------------------------------
// init m (heat max >=0 -> 0 bits) and pmm (min=+inf, max=0)
// ---------------------------------------------------------------------------
__global__ __launch_bounds__(256) void mm_init(unsigned* __restrict__ m_bits,
                                               unsigned* __restrict__ pmm_bits) {
    int i = threadIdx.x;
    if (i < 64) {
        m_bits[i] = 0u;
        pmm_bits[2 * i]     = 0x7F800000u;   // +inf
        pmm_bits[2 * i + 1] = 0u;
    }
}

// ---------------------------------------------------------------------------
// K1: scatter. Grid (6 strips, 8 point-chunks, GB). One wave per point,
// lanes = patch columns. LDS strip accumulate, then skip-zero atomic merge
// into pre-zeroed global heat.
// ---------------------------------------------------------------------------
__global__ __launch_bounds__(256) void heat_scatter(const float* __restrict__ x_t,
                                                    float* __restrict__ heat,
                                                    int b0) {
    const int strip = blockIdx.x;          // 0..5
    const int pc    = blockIdx.y;          // 0..7 point chunks of 128
    const int lb    = blockIdx.z;
    const int b = b0 + lb;
    const int c0 = strip * 64;
    const int cw = min(64, IW - c0);
    __shared__ float lds[IH * 64];
    __shared__ float k1n[64];
    const int tid = threadIdx.x;

    if (tid < 64) {
        float v = 0.0f;
        if (tid < KSZ) {
            float ax = (float)tid - 18.0f;
            v = expf(-ax * ax / 18.0f);    // 2*sigma^2 = 18
        }
        k1n[tid] = v;
    }
    for (int i = tid; i < IH * 64; i += 256) lds[i] = 0.0f;
    __syncthreads();
    if (tid == 0) {
        float s = 0.0f;
        for (int i = 0; i < KSZ; i++) s += k1n[i];
        float inv = 1.0f / s;
        for (int i = 0; i < KSZ; i++) k1n[i] *= inv;
    }
    __syncthreads();

    const int wave = tid >> 6;
    const int lane = tid & 63;
    const float kc = k1n[lane];

    const int pbeg = pc * 128;
    for (int p = pbeg + wave; p < pbeg + 128; p += 4) {
        float x = x_t[(size_t)(b * NT + p) * 2 + 0];
        float y = x_t[(size_t)(b * NT + p) * 2 + 1];
        if (isnan(x) || isnan(y)) continue;
        int xp = IH - (int)((x - 30.0f) * 180.0f);
        int yp = (int)((y - 120.0f) * 165.0f);
        int xs = min(max(xp - 18, 0), IH - 36);
        int xe = min(max(xp + 18, 0), IH);
        int ys = min(max(yp - 18, 0), IW - 36);
        int ye = min(max(yp + 18, 0), IW);
        int nr = xe - xs, nc = ye - ys;
        if (nr <= 0 || nc <= 0) continue;
        int cbeg = max(ys, c0);
        int cend = min(ys + nc, c0 + cw);
        if (cbeg >= cend) continue;        // wave-uniform skip
        int col = ys + lane;
        if ((lane < nc) && (col >= c0) && (col < c0 + cw)) {
            int off = col - c0;
            for (int r = 0; r < nr; r++) {
                atomicAdd(&lds[(xs + r) * 64 + off], k1n[r] * kc);
            }
        }
    }
    __syncthreads();
    for (int i = tid; i < IH * cw; i += 256) {
        int row = i / cw, col = i % cw;
        float v = lds[row * 64 + col];
        if (v != 0.0f)
            atomicAdd(&heat[((size_t)lb * IH + row) * IW + c0 + col], v);
    }
}

// ---------------------------------------------------------------------------
// K2: per-batch max of heat — multi-block + unsigned atomicMax (heat >= 0)
// ---------------------------------------------------------------------------
__global__ __launch_bounds__(256) void heat_max(const float* __restrict__ heat,
                                                unsigned* __restrict__ m_bits) {
    const int chunk = blockIdx.x;          // 0..3
    const int lb = blockIdx.y;
    const int n0 = chunk * (EL_HEAT / 4);
    const int n1 = (chunk == 3) ? EL_HEAT : n0 + (EL_HEAT / 4);
    const float* hb = heat + (size_t)lb * EL_HEAT;
    float mx = 0.0f;
    for (int i = n0 + threadIdx.x; i < n1; i += 256) mx = fmaxf(mx, hb[i]);
    __shared__ float red[256];
    red[threadIdx.x] = mx;
    __syncthreads();
    for (int s = 128; s > 0; s >>= 1) {
        if (threadIdx.x < s) red[threadIdx.x] = fmaxf(red[threadIdx.x], red[threadIdx.x + s]);
        __syncthreads();
    }
    if (threadIdx.x == 0) atomicMax(&m_bits[lb], __float_as_uint(red[0]));
}

// ---------------------------------------------------------------------------
// K3: conv1(1->32) + BN + relu + pool, with fuse folded in:
// in(y,x) = (0.7/(m+1e-10))*heat + 0.3*image
// ---------------------------------------------------------------------------
__global__ __launch_bounds__(256) void conv1_pool(const float* __restrict__ heat,
                                                  const float* __restrict__ image,
                                                  const float* __restrict__ m,
                                                  const float* __restrict__ w,
                                                  const float* __restrict__ cb,
                                                  const float* __restrict__ g,
                                                  const float* __restrict__ bb,
                                                  float* __restrict__ out1,
                                                  int b0, int gb) {
    __shared__ float ws_[CH1 * 9];
    __shared__ float bs_[CH1];
    const int tid = threadIdx.x;
    for (int i = tid; i < CH1 * 9; i += 256) {
        int oc = i / 9;
        ws_[i] = w[i] * g[oc];
    }
    if (tid < CH1) bs_[tid] = cb[tid] * g[tid] + bb[tid];
    __syncthreads();

    int t = blockIdx.x * 256 + tid;
    if (t >= gb * H1 * W1) return;
    int lb = t / (H1 * W1);
    int r = t % (H1 * W1);
    int py = r / W1, px = r % W1;
    const float s = 0.7f / (m[lb] + 1e-10f);
    const float* hb = heat + (size_t)lb * EL_HEAT;
    const float* ib = image + (size_t)(b0 + lb) * EL_HEAT;

    float v[4][4];
    int y0 = 2 * py - 1, x0 = 2 * px - 1;
#pragma unroll
    for (int i = 0; i < 4; i++) {
#pragma unroll
        for (int j = 0; j < 4; j++) {
            int y = y0 + i, x = x0 + j;
            float val = 0.0f;
            if (y >= 0 && y < IH && x >= 0 && x < IW) {
                size_t idx = (size_t)y * IW + x;
                val = s * hb[idx] + 0.3f * ib[idx];
            }
            v[i][j] = val;
        }
    }
    for (int oc = 0; oc < CH1; oc++) {
        float a00 = 0, a01 = 0, a10 = 0, a11 = 0;
        const float* wp = &ws_[oc * 9];
#pragma unroll
        for (int ky = 0; ky < 3; ky++) {
#pragma unroll
            for (int kx = 0; kx < 3; kx++) {
                float wv = wp[ky * 3 + kx];
                a00 += wv * v[ky][kx];
                a01 += wv * v[ky][kx + 1];
                a10 += wv * v[ky + 1][kx];
                a11 += wv * v[ky + 1][kx + 1];
            }
        }
        float bias = bs_[oc];
        a00 = fmaxf(a00 + bias, 0.0f);
        a01 = fmaxf(a01 + bias, 0.0f);
        a10 = fmaxf(a10 + bias, 0.0f);
        a11 = fmaxf(a11 + bias, 0.0f);
        float mx = fmaxf(fmaxf(a00, a01), fmaxf(a10, a11));
        out1[(((size_t)lb * CH1 + oc) * H1 + py) * W1 + px] = mx;
    }
}

// ---------------------------------------------------------------------------
// K4: conv2(32->64) + BN + relu + pool. Output CHANNEL-LAST: [lb][pixel][oc]
// ---------------------------------------------------------------------------
__global__ __launch_bounds__(256) void conv2_pool(const float* __restrict__ in,
                                                  const float* __restrict__ w,
                                                  const float* __restrict__ cb,
                                                  const float* __restrict__ g,
                                                  const float* __restrict__ bb,
                                                  float* __restrict__ out) {
    __shared__ float ws_[8 * CH1 * 9];
    __shared__ float bs_[8];
    const int tid = threadIdx.x;
    const int ocg = blockIdx.y;
    const int lb = blockIdx.z;
    for (int i = tid; i < 8 * CH1 * 9; i += 256) {
        int o = i / (CH1 * 9);
        int rest = i % (CH1 * 9);
        int oc = ocg * 8 + o;
        ws_[i] = w[(size_t)oc * CH1 * 9 + rest] * g[oc];
    }
    if (tid < 8) {
        int oc = ocg * 8 + tid;
        bs_[tid] = cb[oc] * g[oc] + bb[oc];
    }
    __syncthreads();

    int pid = blockIdx.x * 256 + tid;
    if (pid >= PIX2) return;
    int py = pid / W2, px = pid % W2;
    float acc[8][4];
#pragma unroll
    for (int o = 0; o < 8; o++)
#pragma unroll
        for (int q = 0; q < 4; q++) acc[o][q] = 0.0f;

    int y0 = 2 * py - 1, x0 = 2 * px - 1;
    for (int ic = 0; ic < CH1; ic++) {
        float v[4][4];
        const float* ip = in + ((size_t)lb * CH1 + ic) * H1 * W1;
#pragma unroll
        for (int i = 0; i < 4; i++) {
#pragma unroll
            for (int j = 0; j < 4; j++) {
                int y = y0 + i, x = x0 + j;
                v[i][j] = (y >= 0 && y < H1 && x >= 0 && x < W1) ? ip[(size_t)y * W1 + x] : 0.0f;
            }
        }
#pragma unroll
        for (int o = 0; o < 8; o++) {
            const float* wp = &ws_[(o * CH1 + ic) * 9];
#pragma unroll
            for (int ky = 0; ky < 3; ky++) {
#pragma unroll
                for (int kx = 0; kx < 3; kx++) {
                    float wv = wp[ky * 3 + kx];
                    acc[o][0] += wv * v[ky][kx];
                    acc[o][1] += wv * v[ky][kx + 1];
                    acc[o][2] += wv * v[ky + 1][kx];
                    acc[o][3] += wv * v[ky + 1][kx + 1];
                }
            }
        }
    }
    float* ob = out + ((size_t)lb * PIX2 + pid) * CH2 + ocg * 8;
#pragma unroll
    for (int o = 0; o < 8; o++) {
        float bias = bs_[o];
        float a0 = fmaxf(acc[o][0] + bias, 0.0f);
        float a1 = fmaxf(acc[o][1] + bias, 0.0f);
        float a2 = fmaxf(acc[o][2] + bias, 0.0f);
        float a3 = fmaxf(acc[o][3] + bias, 0.0f);
        ob[o] = fmaxf(fmaxf(a0, a1), fmaxf(a2, a3));
    }
}

// ---------------------------------------------------------------------------
// weight fold/transpose: wT[tap][oc][ic] = bf16(w[oc][ic][tap]*g[oc])
// ---------------------------------------------------------------------------
__global__ __launch_bounds__(256) void wfold_k(const float* __restrict__ w,
                                               const float* __restrict__ g,
                                               const float* __restrict__ cb,
                                               const float* __restrict__ bb,
                                               short* __restrict__ wT,
                                               float* __restrict__ bfold,
                                               int IC) {
    int i = blockIdx.x * 256 + threadIdx.x;
    int n = 9 * 128 * IC;
    if (i >= n) return;
    int tap = i / (128 * IC);
    int r = i % (128 * IC);
    int oc = r / IC;
    int ic = r % IC;
    wT[i] = f2bf(w[((size_t)oc * IC + ic) * 9 + tap] * g[oc]);
    if (tap == 0 && ic == 0) bfold[oc] = cb[oc] * g[oc] + bb[oc];
}

// ---------------------------------------------------------------------------
// K5-K8: 3x3 conv via bf16 MFMA, CHANNEL-LAST in/out: in [lb][pixel][IC],
// out [lb][pixel][128]. Block (xt, y, lb); 4 waves each own 32 ocs.
// ---------------------------------------------------------------------------
template <int IC, bool SIG>
__global__ __launch_bounds__(256) void conv3x3_mfma(const float* __restrict__ in,
                                                    const short* __restrict__ wT,
                                                    const float* __restrict__ bfold,
                                                    float* __restrict__ out) {
    const int xt = blockIdx.x;      // 0..5
    const int y  = blockIdx.y;      // 0..44
    const int lb = blockIdx.z;
    const int x0 = xt * 16;
    const int tid = threadIdx.x;
    const int wave = tid >> 6;
    const int lane = tid & 63;
    const int m = lane & 15;
    const int q = lane >> 4;

    constexpr int KC = 32;          // ic chunk
    constexpr int NCH = IC / KC;
    constexpr int AP = 40;          // padded ic stride (2-way max on reads)
    __shared__ __align__(16) short tileA[3 * 18 * AP];

    floatx4 acc0 = {0.f, 0.f, 0.f, 0.f};
    floatx4 acc1 = {0.f, 0.f, 0.f, 0.f};

    const float* inb = in + (size_t)lb * IC * PIX2;

    for (int c = 0; c < NCH; ++c) {
        const int ic0 = c * KC;
        // stage [3 rows][18 x][32 ic] as bf16 via short8 (coalesced, conflict-free)
        {
            const int evec = 3 * 18 * (KC / 8);   // 216
            for (int e = tid; e < evec; e += 256) {
                int dy = e / (18 * (KC / 8));
                int r  = e % (18 * (KC / 8));
                int tx = r / (KC / 8);
                int i8 = r % (KC / 8);
                int yin = y + dy - 1;
                int xin = x0 + tx - 1;
                short8 hv = {0, 0, 0, 0, 0, 0, 0, 0};
                if (yin >= 0 && yin < H2 && xin >= 0 && xin < W2) {
                    const float* src = &inb[((size_t)yin * W2 + xin) * IC + ic0 + i8 * 8];
                    floatx4 f0 = *reinterpret_cast<const floatx4*>(src);
                    floatx4 f1 = *reinterpret_cast<const floatx4*>(src + 4);
                    hv[0] = f2bf(f0[0]); hv[1] = f2bf(f0[1]);
                    hv[2] = f2bf(f0[2]); hv[3] = f2bf(f0[3]);
                    hv[4] = f2bf(f1[0]); hv[5] = f2bf(f1[1]);
                    hv[6] = f2bf(f1[2]); hv[7] = f2bf(f1[3]);
                }
                *reinterpret_cast<short8*>(&tileA[(dy * 18 + tx) * AP + i8 * 8]) = hv;
            }
        }
        __syncthreads();

        const int oc0 = wave * 32 + m;
#pragma unroll
        for (int tap = 0; tap < 9; ++tap) {
            const int dy = tap / 3, dx = tap % 3;
            short8 af = *reinterpret_cast<const short8*>(
                &tileA[(dy * 18 + dx + m) * AP + q * 8]);
            const short* wt = wT + (size_t)tap * 128 * IC;
            short8 b0 = *reinterpret_cast<const short8*>(
                &wt[(size_t)oc0 * IC + ic0 + q * 8]);
            short8 b1 = *reinterpret_cast<const short8*>(
                &wt[(size_t)(oc0 + 16) * IC + ic0 + q * 8]);
            acc0 = __builtin_amdgcn_mfma_f32_16x16x32_bf16(af, b0, acc0, 0, 0, 0);
            acc1 = __builtin_amdgcn_mfma_f32_16x16x32_bf16(af, b1, acc1, 0, 0, 0);
        }
        __syncthreads();
    }

    // epilogue: C[m-pixel = q*4+r, n-oc = m]; channel-last write
    float* outb = out + (size_t)lb * PIX2 * 128;
    const int oc0 = wave * 32 + m;
    const float bias0 = bfold[oc0];
    const float bias1 = bfold[oc0 + 16];
#pragma unroll
    for (int r = 0; r < 4; ++r) {
        int x = x0 + q * 4 + r;
        if (x < W2) {
            float z0 = acc0[r] + bias0;
            float z1 = acc1[r] + bias1;
            if (SIG) {
                z0 = 1.0f / (1.0f + expf(-z0));
                z1 = 1.0f / (1.0f + expf(-z1));
            } else {
                z0 = fmaxf(z0, 0.0f);
                z1 = fmaxf(z1, 0.0f);
            }
            float* op = &outb[((size_t)y * W2 + x) * 128];
            op[oc0] = z0;
            op[oc0 + 16] = z1;
        }
    }
}

// ---------------------------------------------------------------------------
// K9: per-batch min/max of p2 (channel-last, elementwise) — multi-block atomics
// ---------------------------------------------------------------------------
__global__ __launch_bounds__(256) void pminmax(const float* __restrict__ p,
                                               unsigned* __restrict__ pmm_bits) {
    const int chunk = blockIdx.x;          // 0..31
    const int lb = blockIdx.y;
    const int n0 = chunk * (EL_MAP3 / 32);
    const int n1 = (chunk == 31) ? EL_MAP3 : n0 + (EL_MAP3 / 32);
    const float* pb = p + (size_t)lb * EL_MAP3;
    float mn = INFINITY, mx = 0.0f;
    for (int i = n0 + threadIdx.x; i < n1; i += 256) {
        float v = pb[i];
        mn = fminf(mn, v);
        mx = fmaxf(mx, v);
    }
    __shared__ float rmn[256], rmx[256];
    rmn[threadIdx.x] = mn; rmx[threadIdx.x] = mx;
    __syncthreads();
    for (int s = 128; s > 0; s >>= 1) {
        if (threadIdx.x < s) {
            rmn[threadIdx.x] = fminf(rmn[threadIdx.x], rmn[threadIdx.x + s]);
            rmx[threadIdx.x] = fmaxf(rmx[threadIdx.x], rmx[threadIdx.x + s]);
        }
        __syncthreads();
    }
    if (threadIdx.x == 0) {
        atomicMin(&pmm_bits[lb * 2],     __float_as_uint(rmn[0]));
        atomicMax(&pmm_bits[lb * 2 + 1], __float_as_uint(rmx[0]));
    }
}

// ---------------------------------------------------------------------------
// K10: p_map = sigmoid(10*((p-min)/max(max-min,1e-4) - 0.5))  (in place)
// ---------------------------------------------------------------------------
__global__ __launch_bounds__(256) void pmap_k(float* __restrict__ p,
                                              const float* __restrict__ mm,
                                              int n) {
    int i = blockIdx.x * 256 + threadIdx.x;
    if (i >= n) return;
    int lb = i / EL_MAP3;
    float mn = mm[lb * 2], mx = mm[lb * 2 + 1];
    float denom = fmaxf(mx - mn, 1e-4f);
    float v = (p[i] - mn) / denom;
    p[i] = 1.0f / (1.0f + expf(-10.0f * (v - 0.5f)));
}

// ---------------------------------------------------------------------------
// K11: px[p][c] = (1/3690) * sum_hw pm[hw][p] * fx[hw][c]   (channel-last)
// ---------------------------------------------------------------------------
__global__ __launch_bounds__(256) void einsum_k(const float* __restrict__ pm,
                                                const float* __restrict__ fx,
                                                float* __restrict__ px) {
    const int lb = blockIdx.z;
    const int pt = blockIdx.y;
    const int ct = blockIdx.x;
    __shared__ float As[64][33], Bs[64][33];
    const int tid = threadIdx.x;
    const int ty = tid / 16, tx = tid % 16;
    float acc00 = 0, acc01 = 0, acc10 = 0, acc11 = 0;
    const float* A = pm + (size_t)lb * EL_MAP3;
    const float* Bp = fx + (size_t)lb * EL_MAP3;
    for (int kk = 0; kk < PIX2; kk += 64) {
        for (int l = tid; l < 2048; l += 256) {
            int k = l >> 5, ch = l & 31;
            int gk = kk + k;
            float av = 0, bv = 0;
            if (gk < PIX2) {
                av = A[(size_t)gk * CH3 + pt * 32 + ch];
                bv = Bp[(size_t)gk * CH3 + ct * 32 + ch];
            }
            As[k][ch] = av;
            Bs[k][ch] = bv;
        }
        __syncthreads();
#pragma unroll
        for (int k = 0; k < 64; k++) {
            float a0 = As[k][2 * ty], a1 = As[k][2 * ty + 1];
            float b0 = Bs[k][2 * tx], b1 = Bs[k][2 * tx + 1];
            acc00 += a0 * b0; acc01 += a0 * b1;
            acc10 += a1 * b0; acc11 += a1 * b1;
        }
        __syncthreads();
    }
    const float inv = 1.0f / (float)PIX2;
    int p0 = pt * 32 + 2 * ty, c0 = ct * 32 + 2 * tx;
    px[((size_t)lb * CH3 + p0) * CH3 + c0] = acc00 * inv;
    px[((size_t)lb * CH3 + p0) * CH3 + c0 + 1] = acc01 * inv;
    px[((size_t)lb * CH3 + p0 + 1) * CH3 + c0] = acc10 * inv;
    px[((size_t)lb * CH3 + p0 + 1) * CH3 + c0 + 1] = acc11 * inv;
}

// ---------------------------------------------------------------------------
// K12: out[b0+lb,o] = sum_k px[lb,k]*fc_w[o,k] + fc_b[o]  (f32 output)
// ---------------------------------------------------------------------------
__global__ __launch_bounds__(256) void fc_k(const float* __restrict__ px,
                                            const float* __restrict__ w,
                                            const float* __restrict__ bias,
                                            float* __restrict__ out,
                                            int b0) {
    const int gw = blockIdx.x * 4 + (threadIdx.x >> 6);
    const int lane = threadIdx.x & 63;
    const int lb = gw >> 8;
    const int o = gw & 255;
    const float* xb = px + (size_t)lb * EL_PX;
    const float* wr = w + (size_t)o * EL_PX;
    float s = 0.0f;
    for (int k = lane; k < EL_PX; k += 64) s += xb[k] * wr[k];
#pragma unroll
    for (int off = 32; off > 0; off >>= 1) s += __shfl_down(s, off);
    if (lane == 0) out[(size_t)(b0 + lb) * 256 + o] = s + bias[o];
}

// ---------------------------------------------------------------------------
extern "C" void kernel_launch(void* const* d_in, const int* in_sizes, int n_in,
                              void* d_out, int out_size, void* d_ws, size_t ws_size,
                              hipStream_t stream) {
    const float* x_t   = (const float*)d_in[0];
    const float* image = (const float*)d_in[1];
    const float* c1_w  = (const float*)d_in[2];
    const float* c1_b  = (const float*)d_in[3];
    const float* bn1_g = (const float*)d_in[4];
    const float* bn1_b = (const float*)d_in[5];
    const float* c2_w  = (const float*)d_in[6];
    const float* c2_b  = (const float*)d_in[7];
    const float* bn2_g = (const float*)d_in[8];
    const float* bn2_b = (const float*)d_in[9];
    const float* a1_w  = (const float*)d_in[10];
    const float* a1_b  = (const float*)d_in[11];
    const float* abn1_g= (const float*)d_in[12];
    const float* abn1_b= (const float*)d_in[13];
    const float* a2_w  = (const float*)d_in[14];
    const float* a2_b  = (const float*)d_in[15];
    const float* abn2_g= (const float*)d_in[16];
    const float* abn2_b= (const float*)d_in[17];
    const float* p1_w  = (const float*)d_in[18];
    const float* p1_b  = (const float*)d_in[19];
    const float* pbn1_g= (const float*)d_in[20];
    const float* pbn1_b= (const float*)d_in[21];
    const float* p2_w  = (const float*)d_in[22];
    const float* p2_b  = (const float*)d_in[23];
    const float* pbn2_g= (const float*)d_in[24];
    const float* pbn2_b= (const float*)d_in[25];
    const float* fc_w  = (const float*)d_in[26];
    const float* fc_b  = (const float*)d_in[27];
    float* outp = (float*)d_out;

    // Fixed region: folded bf16 weights + biases
    float* ws = (float*)d_ws;
    short* wTa1 = (short*)ws;
    short* wTa2 = wTa1 + WSH_A1;
    short* wTp1 = wTa2 + WSH_A2;
    short* wTp2 = wTp1 + WSH_A1;
    float* bfa1 = ws + WSH_TOT / 2;
    float* bfa2 = bfa1 + 128;
    float* bfp1 = bfa2 + 128;
    float* bfp2 = bfp1 + 128;
    float* dyn  = bfp2 + 128;
    const size_t fixed_floats = WSH_TOT / 2 + 512;

    int GB = 32;
    while (GB > 1) {
        size_t need = ((size_t)GB * EL_PER_BATCH + fixed_floats + 256) * sizeof(float);
        if (need <= ws_size) break;
        GB >>= 1;
    }
    const int ngroups = NB / GB;

    // dynamic regions (overlays: B hosts out1 then pp1; D hosts fbuf then pp2)
    float* heat = dyn;                                // EL_HEAT * GB
    float* m    = heat + (size_t)GB * EL_HEAT;        // 64
    float* regB = m + 64;                             // EL_OUT1 * GB
    float* regC = regB + (size_t)GB * EL_OUT1;        // EL_OUT2 * GB
    float* regD = regC + (size_t)GB * EL_OUT2;        // EL_MAP3 * GB
    float* regE = regD + (size_t)GB * EL_MAP3;        // EL_MAP3 * GB
    float* pmm  = regE + (size_t)GB * EL_MAP3;        // 128
    float* px   = pmm + 128;                          // EL_PX * GB
    // aliases (strides: B uses EL_MAP3 stride when hosting pp1 — use separate
    // per-role base with EL_MAP3 stride; EL_MAP3*GB <= EL_OUT1*GB so it fits)
    float* out1 = regB;   // [lb][CH1][H1][W1]
    float* out2 = regC;   // [lb][PIX2][CH2] channel-last
    float* fbuf = regD;   // [lb][PIX2][128]
    float* fx   = regE;   // [lb][PIX2][128]
    float* pp1  = regB;   // [lb][PIX2][128] (out1 dead)
    float* pp2  = regD;   // (fbuf dead)

    // fold weights
    wfold_k<<<(9 * 128 * CH2 + 255) / 256, 256, 0, stream>>>(a1_w, abn1_g, a1_b, abn1_b, wTa1, bfa1, CH2);
    wfold_k<<<(9 * 128 * CH3 + 255) / 256, 256, 0, stream>>>(a2_w, abn2_g, a2_b, abn2_b, wTa2, bfa2, CH3);
    wfold_k<<<(9 * 128 * CH2 + 255) / 256, 256, 0, stream>>>(p1_w, pbn1_g, p1_b, pbn1_b, wTp1, bfp1, CH2);
    wfold_k<<<(9 * 128 * CH3 + 255) / 256, 256, 0, stream>>>(p2_w, pbn2_g, p2_b, pbn2_b, wTp2, bfp2, CH3);

    const int ptiles = (PIX2 + 255) / 256;   // 15

    for (int gidx = 0; gidx < ngroups; ++gidx) {
        const int b0 = gidx * GB;
        mm_init<<<1, 256, 0, stream>>>((unsigned*)m, (unsigned*)pmm);
        {
            int n = GB * EL_HEAT;
            zero_k<<<(n + 255) / 256, 256, 0, stream>>>(heat, n);
        }
        heat_scatter<<<dim3(6, 8, GB), 256, 0, stream>>>(x_t, heat, b0);
        heat_max<<<dim3(4, GB), 256, 0, stream>>>(heat, (unsigned*)m);
        conv1_pool<<<(GB * H1 * W1 + 255) / 256, 256, 0, stream>>>(
            heat, image, m, c1_w, c1_b, bn1_g, bn1_b, out1, b0, GB);
        conv2_pool<<<dim3(ptiles, CH2 / 8, GB), 256, 0, stream>>>(
            out1, c2_w, c2_b, bn2_g, bn2_b, out2);
        conv3x3_mfma<CH2, false><<<dim3(6, H2, GB), 256, 0, stream>>>(out2, wTa1, bfa1, fbuf);
        conv3x3_mfma<CH3, true ><<<dim3(6, H2, GB), 256, 0, stream>>>(fbuf, wTa2, bfa2, fx);
        conv3x3_mfma<CH2, false><<<dim3(6, H2, GB), 256, 0, stream>>>(out2, wTp1, bfp1, pp1);
        conv3x3_mfma<CH3, false><<<dim3(6, H2, GB), 256, 0, stream>>>(pp1, wTp2, bfp2, pp2);
        pminmax<<<dim3(32, GB), 256, 0, stream>>>(pp2, (unsigned*)pmm);
        {
            int n = GB * EL_MAP3;
            pmap_k<<<(n + 255) / 256, 256, 0, stream>>>(pp2, pmm, n);
        }
        einsum_k<<<dim3(4, 4, GB), 256, 0, stream>>>(pp2, fx, px);
        fc_k<<<GB * 64, 256, 0, stream>>>(px, fc_w, fc_b, outp, b0);
    }
}